// Round 4
// baseline (590.214 us; speedup 1.0000x reference)
//
#include <hip/hip_runtime.h>

// R7 (bisect + wave-local): one 64-thread block = ONE wave owning 16 samples.
// z dataflow is R3-VERBATIM (zgenv template, z LDS layout [s:264][u:16][v],
// pack2f, A-read srow*264 + quad*8 + c*32 + rt*4224, W3 pack kernel) but kept
// entirely wave-local: 3 z slots (25.3 KB), single-wave barriers (~free), no
// cross-wave reduction. a stays in registers (no lds_a); b staged to LDS
// (R3 layout, stride 148). Each wave computes all 4 wtiles over full K in
// 3 output-l passes (acc <= 80 VGPR). New-vs-R3 surface is only: vi-vectorized
// phase-0, b staging, per-wave epilogue.

typedef __attribute__((ext_vector_type(4))) float f32x4;
typedef __attribute__((ext_vector_type(4))) float f4;
typedef __attribute__((ext_vector_type(2))) float f2;
typedef __attribute__((ext_vector_type(8))) short short8;
typedef unsigned short ushort_t;
typedef unsigned int uint32;

__device__ __forceinline__ uint32 bfb(float x) {
  uint32 u = __float_as_uint(x);
  return (u + 0x7fffu + ((u >> 16) & 1u)) >> 16;  // RNE fp32->bf16 (pack kernel)
}
// round-half-away pack of 2 fp32 -> packed bf16x2: 2 adds + 1 v_perm
__device__ __forceinline__ uint32 pack2f(f2 z) {
  uint32 lo = __float_as_uint(z.x) + 0x8000u;
  uint32 hi = __float_as_uint(z.y) + 0x8000u;
  return __builtin_amdgcn_perm(hi, lo, 0x07060302u);
}

#define C2   0.7071067811865476f
#define C3   0.5773502691896258f
#define C5   0.4472135954999579f
#define C6   0.4082482904638631f
#define C23  0.8164965809277260f
#define C10  0.3162277660168379f
#define C210 0.6324555320336759f
#define C310 0.5477225575051661f
#define C14  0.2672612419124244f
#define C214 0.5345224838248488f
#define C314 0.4629100498862757f

// ---------------- W3 pre-pack: VERBATIM the harness-verified R3 kernel --------
__global__ __launch_bounds__(256) void pack_w3_kernel(
    const float* __restrict__ W30, const float* __restrict__ W31,
    const float* __restrict__ W32, ushort_t* __restrict__ pack) {
  int lc = blockIdx.x;
  int t = threadIdx.x >> 6;
  int lam = threadIdx.x & 63;
  const float* W;
  int mb;
  float nrm;
  if (lc < 24) {
    W = W30; mb = lc * 32; nrm = 0.036084391824351615f;        // 1/sqrt(768)
  } else if (lc < 72) {
    W = W31; mb = (lc - 24) * 32; nrm = 0.025515518153991442f; // 1/sqrt(1536)
  } else {
    W = W32; mb = (lc - 72) * 32; nrm = 0.025515518153991442f;
  }
  int w = t * 16 + (lam & 15);
  int m0 = mb + (lam >> 4) * 8;
  ushort_t* dst = pack + ((size_t)(lc * 4 + t) * 64 + lam) * 8;
#pragma unroll
  for (int j = 0; j < 8; ++j)
    dst[j] = (ushort_t)bfb(W[(size_t)(m0 + j) * 64 + w] * nrm);
}

// ---------------- z generation: VERBATIM R3 ----------------
// bsj: [j][16 v] floats; writes NK slots at zrow + k*4224 (slot = 16 rows x 264)
template <int NK, int JD, class F>
__device__ __forceinline__ void zgenv(const float* bsj, ushort_t* zrow, F f) {
  uint32 zp[NK][8];
#pragma unroll
  for (int oc = 0; oc < 2; ++oc) {
    f2 bb4[JD][4];
#pragma unroll
    for (int j = 0; j < JD; ++j) {
      f4 lo = *(const f4*)(bsj + j * 16 + oc * 8);
      f4 hi = *(const f4*)(bsj + j * 16 + oc * 8 + 4);
      bb4[j][0] = lo.xy; bb4[j][1] = lo.zw;
      bb4[j][2] = hi.xy; bb4[j][3] = hi.zw;
    }
#pragma unroll
    for (int qp = 0; qp < 4; ++qp) {
      f2 bcol[JD], z[NK];
#pragma unroll
      for (int j = 0; j < JD; ++j) bcol[j] = bb4[j][qp];
      f(bcol, z);
#pragma unroll
      for (int k = 0; k < NK; ++k) zp[k][oc * 4 + qp] = pack2f(z[k]);
    }
  }
#pragma unroll
  for (int k = 0; k < NK; ++k) {
    uint32* d = (uint32*)(zrow + k * (16 * 264));
    *(uint4*)(d) = make_uint4(zp[k][0], zp[k][1], zp[k][2], zp[k][3]);
    *(uint4*)(d + 4) = make_uint4(zp[k][4], zp[k][5], zp[k][6], zp[k][7]);
  }
}

// ---------------- MFMA: R3-verbatim A addressing, full K (8 chunks), 4 wtiles --
template <int NROW, int NC, int M0>
__device__ __forceinline__ void mfma_full(const ushort_t* zb,
                                          const ushort_t* pkl, int pcbase,
                                          int lane, f32x4 (&acc)[4][NC]) {
  const int srow = lane & 15, quad = lane >> 4;
  const ushort_t* ab = zb + srow * 264 + quad * 8;
#pragma unroll
  for (int c = 0; c < 8; ++c) {
    const ushort_t* bb = pkl + (size_t)(pcbase + c) * 2048;
    short8 B0 = *(const short8*)(bb);
    short8 B1 = *(const short8*)(bb + 512);
    short8 B2 = *(const short8*)(bb + 1024);
    short8 B3 = *(const short8*)(bb + 1536);
#pragma unroll
    for (int rt = 0; rt < NROW; ++rt) {
      short8 A = *(const short8*)(ab + rt * 4224 + c * 32);
      acc[0][M0 + rt] = __builtin_amdgcn_mfma_f32_16x16x32_bf16(A, B0, acc[0][M0 + rt], 0, 0, 0);
      acc[1][M0 + rt] = __builtin_amdgcn_mfma_f32_16x16x32_bf16(A, B1, acc[1][M0 + rt], 0, 0, 0);
      acc[2][M0 + rt] = __builtin_amdgcn_mfma_f32_16x16x32_bf16(A, B2, acc[2][M0 + rt], 0, 0, 0);
      acc[3][M0 + rt] = __builtin_amdgcn_mfma_f32_16x16x32_bf16(A, B3, acc[3][M0 + rt], 0, 0, 0);
    }
  }
}

// ---------------- main fused kernel (one wave per block) ----------------
__global__ __launch_bounds__(64, 1) void tdense_kernel(
    const float* __restrict__ x0, const float* __restrict__ x1,
    const float* __restrict__ x2, const float* __restrict__ W10,
    const float* __restrict__ W20, const float* __restrict__ W11,
    const float* __restrict__ W21, const float* __restrict__ W12,
    const float* __restrict__ W22, const ushort_t* __restrict__ pack,
    float* __restrict__ out) {
  __shared__ __align__(16) float lds_b[16 * 148];          // 9472 B, R3 layout
  __shared__ __align__(16) ushort_t zls[3 * 16 * 264];     // 25344 B, 3 z slots

  const int lane = threadIdx.x;    // 0..63
  const int s = lane & 15, q = lane >> 4;
  const int nbase = blockIdx.x * 16;
  const int n = nbase + s;

  // ---- Phase 0: both branch linears for v-columns q*4..q*4+3 (f4 W loads) ----
  const float* px0 = x0 + (size_t)n * 64;
  const float* px1 = x1 + (size_t)n * 192;
  const float* px2 = x2 + (size_t)n * 320;
  float av_[4][9], bv_[4][9];
#pragma unroll
  for (int vi = 0; vi < 4; ++vi)
#pragma unroll
    for (int i = 0; i < 9; ++i) { av_[vi][i] = 0.f; bv_[vi][i] = 0.f; }
  const int wq = q * 4;
  for (int u4 = 0; u4 < 16; ++u4) {
    f4 xv0 = *(const f4*)(px0 + u4 * 4);
    f4 xa = *(const f4*)(px1 + u4 * 12);
    f4 xb = *(const f4*)(px1 + u4 * 12 + 4);
    f4 xc = *(const f4*)(px1 + u4 * 12 + 8);
    f4 ya = *(const f4*)(px2 + u4 * 20);
    f4 yb = *(const f4*)(px2 + u4 * 20 + 4);
    f4 yc = *(const f4*)(px2 + u4 * 20 + 8);
    f4 yd = *(const f4*)(px2 + u4 * 20 + 12);
    f4 ye = *(const f4*)(px2 + u4 * 20 + 16);
    float x1e[12], x2e[20];
#pragma unroll
    for (int e = 0; e < 4; ++e) { x1e[e] = xa[e]; x1e[4 + e] = xb[e]; x1e[8 + e] = xc[e]; }
#pragma unroll
    for (int e = 0; e < 4; ++e) {
      x2e[e] = ya[e]; x2e[4 + e] = yb[e]; x2e[8 + e] = yc[e];
      x2e[12 + e] = yd[e]; x2e[16 + e] = ye[e];
    }
#pragma unroll
    for (int r = 0; r < 4; ++r) {
      int u = u4 * 4 + r;
      f4 wa0 = *(const f4*)(W10 + u * 16 + wq);
      f4 wb0 = *(const f4*)(W20 + u * 16 + wq);
      f4 wa1 = *(const f4*)(W11 + u * 16 + wq);
      f4 wb1 = *(const f4*)(W21 + u * 16 + wq);
      f4 wa2 = *(const f4*)(W12 + u * 16 + wq);
      f4 wb2 = *(const f4*)(W22 + u * 16 + wq);
      float xx = xv0[r];
      float e0 = x1e[r * 3], e1 = x1e[r * 3 + 1], e2 = x1e[r * 3 + 2];
#pragma unroll
      for (int vi = 0; vi < 4; ++vi) {
        av_[vi][0] += xx * wa0[vi]; bv_[vi][0] += xx * wb0[vi];
        av_[vi][1] += e0 * wa1[vi]; av_[vi][2] += e1 * wa1[vi]; av_[vi][3] += e2 * wa1[vi];
        bv_[vi][1] += e0 * wb1[vi]; bv_[vi][2] += e1 * wb1[vi]; bv_[vi][3] += e2 * wb1[vi];
#pragma unroll
        for (int jj = 0; jj < 5; ++jj) {
          float ev = x2e[r * 5 + jj];
          av_[vi][4 + jj] += ev * wa2[vi];
          bv_[vi][4 + jj] += ev * wb2[vi];
        }
      }
    }
  }

  // ---- normalize a (registers) and stage b to LDS (R3 layout, stride 148) ----
  const float inv8 = 0.125f;
#pragma unroll
  for (int vi = 0; vi < 4; ++vi)
#pragma unroll
    for (int i = 0; i < 9; ++i) av_[vi][i] *= inv8;
#pragma unroll
  for (int j = 0; j < 9; ++j) {
    f4 bw = {bv_[0][j], bv_[1][j], bv_[2][j], bv_[3][j]};
    *(f4*)(lds_b + s * 148 + j * 16 + q * 4) = bw * inv8;
  }
  __syncthreads();

  const float* bsl0 = lds_b + s * 148;
  const float* bsl1 = bsl0 + 16;
  const float* bsl2 = bsl0 + 64;
  const ushort_t* pkl = pack + (size_t)lane * 8;
  ushort_t* zr = zls + s * 264 + (q * 4) * 16;  // this thread's first u-row
  const int ncol = s, rq4 = q * 4;

  // ===== Pass A: output l=0 (p000@pc0 slot0, p110@pc8 slot1, p220@pc16 slot2) =====
  {
    f32x4 acc[4][1];
#pragma unroll
    for (int wt = 0; wt < 4; ++wt) acc[wt][0] = (f32x4)(0.f);
#pragma unroll
    for (int vi = 0; vi < 4; ++vi) {
      const float* arp = av_[vi];
      ushort_t* zv = zr + vi * 16;
      zgenv<1, 1>(bsl0, zv, [&](const f2* b, f2* z) { z[0] = arp[0] * b[0]; });
      zgenv<1, 3>(bsl1, zv + 4224, [&](const f2* b, f2* z) {
        z[0] = -C3 * (arp[1] * b[0] + arp[2] * b[1] + arp[3] * b[2]);
      });
      zgenv<1, 5>(bsl2, zv + 8448, [&](const f2* b, f2* z) {
        z[0] = C5 * (arp[4] * b[0] + arp[5] * b[1] + arp[6] * b[2] +
                     arp[7] * b[3] + arp[8] * b[4]);
      });
    }
    __syncthreads();
    mfma_full<1, 1, 0>(zls, pkl, 0, lane, acc);
    mfma_full<1, 1, 0>(zls + 4224, pkl, 8, lane, acc);
    mfma_full<1, 1, 0>(zls + 8448, pkl, 16, lane, acc);
#pragma unroll
    for (int r = 0; r < 4; ++r) {
      float* row = out + (size_t)(nbase + rq4 + r) * 576;
#pragma unroll
      for (int wt = 0; wt < 4; ++wt) row[wt * 16 + ncol] = acc[wt][0][r];
    }
    __syncthreads();
  }

  // ===== Pass B: output l=1 (011@24, 101@32, 111@40, 121@48, 211@56, 221@64) =====
  {
    f32x4 acc[4][3];
#pragma unroll
    for (int wt = 0; wt < 4; ++wt)
#pragma unroll
      for (int m = 0; m < 3; ++m) acc[wt][m] = (f32x4)(0.f);

#pragma unroll
    for (int vi = 0; vi < 4; ++vi) {
      const float* arp = av_[vi];
      zgenv<3, 3>(bsl1, zr + vi * 16, [&](const f2* b, f2* z) {
        z[0] = arp[0] * b[0]; z[1] = arp[0] * b[1]; z[2] = arp[0] * b[2];
      });
    }
    __syncthreads();
    mfma_full<3, 3, 0>(zls, pkl, 24, lane, acc);
    __syncthreads();

#pragma unroll
    for (int vi = 0; vi < 4; ++vi) {
      const float* arp = av_[vi];
      zgenv<3, 1>(bsl0, zr + vi * 16, [&](const f2* b, f2* z) {
        z[0] = arp[1] * b[0]; z[1] = arp[2] * b[0]; z[2] = arp[3] * b[0];
      });
    }
    __syncthreads();
    mfma_full<3, 3, 0>(zls, pkl, 32, lane, acc);
    __syncthreads();

#pragma unroll
    for (int vi = 0; vi < 4; ++vi) {
      const float* arp = av_[vi];
      zgenv<3, 3>(bsl1, zr + vi * 16, [&](const f2* b, f2* z) {
        z[0] = C2 * (arp[2] * b[2] - arp[3] * b[1]);
        z[1] = C2 * (arp[3] * b[0] - arp[1] * b[2]);
        z[2] = C2 * (arp[1] * b[1] - arp[2] * b[0]);
      });
    }
    __syncthreads();
    mfma_full<3, 3, 0>(zls, pkl, 40, lane, acc);
    __syncthreads();

#pragma unroll
    for (int vi = 0; vi < 4; ++vi) {
      const float* arp = av_[vi];
      zgenv<3, 5>(bsl2, zr + vi * 16, [&](const f2* b, f2* z) {
        z[0] = -C310 * arp[2] * b[1] + C10 * arp[1] * b[2] - C310 * arp[3] * b[0] +
               C310 * arp[1] * b[4];
        z[1] = -C210 * arp[2] * b[2] - C310 * arp[3] * b[3] - C310 * arp[1] * b[1];
        z[2] = -C310 * arp[2] * b[3] + C10 * arp[3] * b[2] - C310 * arp[1] * b[0] -
               C310 * arp[3] * b[4];
      });
    }
    __syncthreads();
    mfma_full<3, 3, 0>(zls, pkl, 48, lane, acc);
    __syncthreads();

#pragma unroll
    for (int vi = 0; vi < 4; ++vi) {
      const float* arp = av_[vi];
      zgenv<3, 3>(bsl1, zr + vi * 16, [&](const f2* b, f2* z) {
        z[0] = -C310 * arp[5] * b[1] + C10 * arp[6] * b[0] - C310 * arp[4] * b[2] +
               C310 * arp[8] * b[0];
        z[1] = -C210 * arp[6] * b[1] - C310 * arp[7] * b[2] - C310 * arp[5] * b[0];
        z[2] = -C310 * arp[7] * b[1] + C10 * arp[6] * b[2] - C310 * arp[4] * b[0] -
               C310 * arp[8] * b[2];
      });
    }
    __syncthreads();
    mfma_full<3, 3, 0>(zls, pkl, 56, lane, acc);
    __syncthreads();

#pragma unroll
    for (int vi = 0; vi < 4; ++vi) {
      const float* arp = av_[vi];
      zgenv<3, 5>(bsl2, zr + vi * 16, [&](const f2* b, f2* z) {
        z[0] = C10 * (arp[8] * b[3] - arp[7] * b[4] + arp[4] * b[1] - arp[5] * b[0]) +
               C310 * (arp[7] * b[2] - arp[6] * b[3]);
        z[1] = C10 * (arp[5] * b[3] - arp[7] * b[1]) +
               C210 * (arp[4] * b[4] - arp[8] * b[0]);
        z[2] = C10 * (arp[8] * b[1] - arp[5] * b[4] + arp[7] * b[0] - arp[4] * b[3]) +
               C310 * (arp[6] * b[1] - arp[5] * b[2]);
      });
    }
    __syncthreads();
    mfma_full<3, 3, 0>(zls, pkl, 64, lane, acc);

#pragma unroll
    for (int r = 0; r < 4; ++r) {
      float* row = out + (size_t)(nbase + rq4 + r) * 576 + 64;
#pragma unroll
      for (int wt = 0; wt < 4; ++wt) {
        int w3 = (wt * 16 + ncol) * 3;
#pragma unroll
        for (int m = 0; m < 3; ++m) row[w3 + m] = acc[wt][m][r];
      }
    }
    __syncthreads();
  }

  // ===== Pass C: output l=2 (022@72, 112@80, 122@88, 202@96, 212@104, 222@112) =====
  {
    f32x4 acc[4][5];
#pragma unroll
    for (int wt = 0; wt < 4; ++wt)
#pragma unroll
      for (int m = 0; m < 5; ++m) acc[wt][m] = (f32x4)(0.f);

    // p022 rows 0-2 / rows 3-4
#pragma unroll
    for (int vi = 0; vi < 4; ++vi) {
      const float* arp = av_[vi];
      zgenv<3, 5>(bsl2, zr + vi * 16, [&](const f2* b, f2* z) {
        z[0] = arp[0] * b[0]; z[1] = arp[0] * b[1]; z[2] = arp[0] * b[2];
      });
    }
    __syncthreads();
    mfma_full<3, 5, 0>(zls, pkl, 72, lane, acc);
    __syncthreads();
#pragma unroll
    for (int vi = 0; vi < 4; ++vi) {
      const float* arp = av_[vi];
      zgenv<2, 5>(bsl2, zr + vi * 16, [&](const f2* b, f2* z) {
        z[0] = arp[0] * b[3]; z[1] = arp[0] * b[4];
      });
    }
    __syncthreads();
    mfma_full<2, 5, 3>(zls, pkl, 72, lane, acc);
    __syncthreads();

    // p112 rows 0-2 / rows 3-4
#pragma unroll
    for (int vi = 0; vi < 4; ++vi) {
      const float* arp = av_[vi];
      zgenv<3, 3>(bsl1, zr + vi * 16, [&](const f2* b, f2* z) {
        z[0] = C2 * (arp[1] * b[2] + arp[3] * b[0]);
        z[1] = C2 * (arp[2] * b[0] + arp[1] * b[1]);
        z[2] = C23 * arp[2] * b[1] - C6 * (arp[1] * b[0] + arp[3] * b[2]);
      });
    }
    __syncthreads();
    mfma_full<3, 5, 0>(zls, pkl, 80, lane, acc);
    __syncthreads();
#pragma unroll
    for (int vi = 0; vi < 4; ++vi) {
      const float* arp = av_[vi];
      zgenv<2, 3>(bsl1, zr + vi * 16, [&](const f2* b, f2* z) {
        z[0] = C2 * (arp[2] * b[2] + arp[3] * b[1]);
        z[1] = C2 * (arp[3] * b[2] - arp[1] * b[0]);
      });
    }
    __syncthreads();
    mfma_full<2, 5, 3>(zls, pkl, 80, lane, acc);
    __syncthreads();

    // p122 rows 0-2 / rows 3-4
#pragma unroll
    for (int vi = 0; vi < 4; ++vi) {
      const float* arp = av_[vi];
      zgenv<3, 5>(bsl2, zr + vi * 16, [&](const f2* b, f2* z) {
        z[0] = C23 * arp[2] * b[4] + C6 * arp[1] * b[1] - C6 * arp[3] * b[3];
        z[1] = C6 * arp[2] * b[3] - C6 * arp[1] * b[0] - C2 * arp[3] * b[2] -
               C6 * arp[3] * b[4];
        z[2] = C2 * (arp[3] * b[1] - arp[1] * b[3]);
      });
    }
    __syncthreads();
    mfma_full<3, 5, 0>(zls, pkl, 88, lane, acc);
    __syncthreads();
#pragma unroll
    for (int vi = 0; vi < 4; ++vi) {
      const float* arp = av_[vi];
      zgenv<2, 5>(bsl2, zr + vi * 16, [&](const f2* b, f2* z) {
        z[0] = -C6 * arp[2] * b[1] + C2 * arp[1] * b[2] + C6 * arp[3] * b[0] -
               C6 * arp[1] * b[4];
        z[1] = -C23 * arp[2] * b[0] + C6 * arp[1] * b[3] + C6 * arp[3] * b[1];
      });
    }
    __syncthreads();
    mfma_full<2, 5, 3>(zls, pkl, 88, lane, acc);
    __syncthreads();

    // p202 rows 0-2 / rows 3-4
#pragma unroll
    for (int vi = 0; vi < 4; ++vi) {
      const float* arp = av_[vi];
      zgenv<3, 1>(bsl0, zr + vi * 16, [&](const f2* b, f2* z) {
        z[0] = arp[4] * b[0]; z[1] = arp[5] * b[0]; z[2] = arp[6] * b[0];
      });
    }
    __syncthreads();
    mfma_full<3, 5, 0>(zls, pkl, 96, lane, acc);
    __syncthreads();
#pragma unroll
    for (int vi = 0; vi < 4; ++vi) {
      const float* arp = av_[vi];
      zgenv<2, 1>(bsl0, zr + vi * 16, [&](const f2* b, f2* z) {
        z[0] = arp[7] * b[0]; z[1] = arp[8] * b[0];
      });
    }
    __syncthreads();
    mfma_full<2, 5, 3>(zls, pkl, 96, lane, acc);
    __syncthreads();

    // p212 rows 0-2 / rows 3-4
#pragma unroll
    for (int vi = 0; vi < 4; ++vi) {
      const float* arp = av_[vi];
      zgenv<3, 3>(bsl1, zr + vi * 16, [&](const f2* b, f2* z) {
        z[0] = -C23 * arp[8] * b[1] - C6 * arp[5] * b[0] + C6 * arp[7] * b[2];
        z[1] = -C6 * arp[7] * b[1] + C6 * arp[4] * b[0] + C2 * arp[6] * b[2] +
               C6 * arp[8] * b[2];
        z[2] = C2 * (arp[7] * b[0] - arp[5] * b[2]);
      });
    }
    __syncthreads();
    mfma_full<3, 5, 0>(zls, pkl, 104, lane, acc);
    __syncthreads();
#pragma unroll
    for (int vi = 0; vi < 4; ++vi) {
      const float* arp = av_[vi];
      zgenv<2, 3>(bsl1, zr + vi * 16, [&](const f2* b, f2* z) {
        z[0] = C6 * arp[5] * b[1] - C2 * arp[6] * b[0] - C6 * arp[4] * b[2] +
               C6 * arp[8] * b[0];
        z[1] = C23 * arp[4] * b[1] - C6 * arp[7] * b[0] - C6 * arp[5] * b[2];
      });
    }
    __syncthreads();
    mfma_full<2, 5, 3>(zls, pkl, 104, lane, acc);
    __syncthreads();

    // p222 rows 0-2 / rows 3-4
#pragma unroll
    for (int vi = 0; vi < 4; ++vi) {
      const float* arp = av_[vi];
      zgenv<3, 5>(bsl2, zr + vi * 16, [&](const f2* b, f2* z) {
        z[0] = C214 * (arp[6] * b[0] + arp[4] * b[2]) -
               C314 * (arp[5] * b[3] + arp[7] * b[1]);
        z[1] = -C14 * (arp[6] * b[1] + arp[5] * b[2]) +
               C314 * (arp[5] * b[4] + arp[8] * b[1]) -
               C314 * (arp[7] * b[0] + arp[4] * b[3]);
        z[2] = -C214 * arp[6] * b[2] - C14 * (arp[5] * b[1] + arp[7] * b[3]) +
               C214 * (arp[4] * b[0] + arp[8] * b[4]);
      });
    }
    __syncthreads();
    mfma_full<3, 5, 0>(zls, pkl, 112, lane, acc);
    __syncthreads();
#pragma unroll
    for (int vi = 0; vi < 4; ++vi) {
      const float* arp = av_[vi];
      zgenv<2, 5>(bsl2, zr + vi * 16, [&](const f2* b, f2* z) {
        z[0] = -C14 * (arp[6] * b[3] + arp[7] * b[2]) -
               C314 * (arp[5] * b[0] + arp[4] * b[1]) -
               C314 * (arp[7] * b[4] + arp[8] * b[3]);
        z[1] = C214 * (arp[6] * b[4] + arp[8] * b[2]) +
               C314 * (arp[5] * b[1] - arp[7] * b[3]);
      });
    }
    __syncthreads();
    mfma_full<2, 5, 3>(zls, pkl, 112, lane, acc);

#pragma unroll
    for (int r = 0; r < 4; ++r) {
      float* row = out + (size_t)(nbase + rq4 + r) * 576 + 256;
#pragma unroll
      for (int wt = 0; wt < 4; ++wt) {
        int w5 = (wt * 16 + ncol) * 5;
#pragma unroll
        for (int m = 0; m < 5; ++m) row[w5 + m] = acc[wt][m][r];
      }
    }
  }
}

extern "C" void kernel_launch(void* const* d_in, const int* in_sizes, int n_in,
                              void* d_out, int out_size, void* d_ws, size_t ws_size,
                              hipStream_t stream) {
  const float* x0 = (const float*)d_in[0];
  const float* x1 = (const float*)d_in[1];
  const float* x2 = (const float*)d_in[2];
  const float* W10 = (const float*)d_in[3];
  const float* W20 = (const float*)d_in[4];
  const float* W11 = (const float*)d_in[5];
  const float* W21 = (const float*)d_in[6];
  const float* W12 = (const float*)d_in[7];
  const float* W22 = (const float*)d_in[8];
  const float* W30 = (const float*)d_in[9];
  const float* W31 = (const float*)d_in[10];
  const float* W32 = (const float*)d_in[11];
  ushort_t* pack = (ushort_t*)d_ws;  // 491,520 bytes used

  hipLaunchKernelGGL(pack_w3_kernel, dim3(120), dim3(256), 0, stream,
                     W30, W31, W32, pack);

  int nsamp = in_sizes[0] / 64;   // 20000
  int nblocks = nsamp / 16;       // 1250 one-wave blocks
  hipLaunchKernelGGL(tdense_kernel, dim3(nblocks), dim3(64), 0, stream,
                     x0, x1, x2, W10, W20, W11, W21, W12, W22, pack,
                     (float*)d_out);
}

// Round 8
// 225.256 us; speedup vs baseline: 2.6202x; 2.6202x over previous
//
#include <hip/hip_runtime.h>

// R11 = R10 resubmit (round-7 result was an infra failure, no data).
// R10 = R3 (harness-verified, 138.8 us) + s_setprio(1/0) around the MFMA inner
// loop (zero-correctness-risk scheduler hint; R3's 2 blocks/CU are barrier-
// desynced across blocks -> role diversity for the CU scheduler to arbitrate).
// Everything else verbatim R3: K-split x w-pair wave tiling, ping-pong z
// buffers, ONE barrier per round (19 rounds), cross-wave h-reduction via LDS.

typedef __attribute__((ext_vector_type(4))) float f32x4;
typedef __attribute__((ext_vector_type(4))) float f4;
typedef __attribute__((ext_vector_type(2))) float f2;
typedef __attribute__((ext_vector_type(8))) short short8;
typedef unsigned short ushort_t;
typedef unsigned int uint32;

__device__ __forceinline__ uint32 bfb(float x) {
  uint32 u = __float_as_uint(x);
  return (u + 0x7fffu + ((u >> 16) & 1u)) >> 16;  // RNE fp32->bf16 (pack kernel)
}
// round-half-away pack of 2 fp32 -> packed bf16x2: 2 adds + 1 v_perm
__device__ __forceinline__ uint32 pack2f(f2 z) {
  uint32 lo = __float_as_uint(z.x) + 0x8000u;
  uint32 hi = __float_as_uint(z.y) + 0x8000u;
  return __builtin_amdgcn_perm(hi, lo, 0x07060302u);
}

#define C2   0.7071067811865476f
#define C3   0.5773502691896258f
#define C5   0.4472135954999579f
#define C6   0.4082482904638631f
#define C23  0.8164965809277260f
#define C10  0.3162277660168379f
#define C210 0.6324555320336759f
#define C310 0.5477225575051661f
#define C14  0.2672612419124244f
#define C214 0.5345224838248488f
#define C314 0.4629100498862757f

// ---------------- W3 pre-pack: B-fragment order, bf16, norm folded ----------------
__global__ __launch_bounds__(256) void pack_w3_kernel(
    const float* __restrict__ W30, const float* __restrict__ W31,
    const float* __restrict__ W32, ushort_t* __restrict__ pack) {
  int lc = blockIdx.x;
  int t = threadIdx.x >> 6;
  int lam = threadIdx.x & 63;
  const float* W;
  int mb;
  float nrm;
  if (lc < 24) {
    W = W30; mb = lc * 32; nrm = 0.036084391824351615f;        // 1/sqrt(768)
  } else if (lc < 72) {
    W = W31; mb = (lc - 24) * 32; nrm = 0.025515518153991442f; // 1/sqrt(1536)
  } else {
    W = W32; mb = (lc - 72) * 32; nrm = 0.025515518153991442f;
  }
  int w = t * 16 + (lam & 15);
  int m0 = mb + (lam >> 4) * 8;
  ushort_t* dst = pack + ((size_t)(lc * 4 + t) * 64 + lam) * 8;
#pragma unroll
  for (int j = 0; j < 8; ++j)
    dst[j] = (ushort_t)bfb(W[(size_t)(m0 + j) * 64 + w] * nrm);
}

// ---------------- z generation (unchanged from R2/R3) ----------------
// b_s: [s][9 jslots][16 v] floats, s-stride 148 (20 mod 32 -> conflict-free bcast)
template <int NK, int JD, class F>
__device__ __forceinline__ void zgenv(const float* bsj, ushort_t* zrow, F f) {
  uint32 zp[NK][8];
#pragma unroll
  for (int oc = 0; oc < 2; ++oc) {
    f2 bb4[JD][4];
#pragma unroll
    for (int j = 0; j < JD; ++j) {
      f4 lo = *(const f4*)(bsj + j * 16 + oc * 8);
      f4 hi = *(const f4*)(bsj + j * 16 + oc * 8 + 4);
      bb4[j][0] = lo.xy; bb4[j][1] = lo.zw;
      bb4[j][2] = hi.xy; bb4[j][3] = hi.zw;
    }
#pragma unroll
    for (int q = 0; q < 4; ++q) {
      f2 bcol[JD], z[NK];
#pragma unroll
      for (int j = 0; j < JD; ++j) bcol[j] = bb4[j][q];
      f(bcol, z);
#pragma unroll
      for (int k = 0; k < NK; ++k) zp[k][oc * 4 + q] = pack2f(z[k]);
    }
  }
#pragma unroll
  for (int k = 0; k < NK; ++k) {
    uint32* d = (uint32*)(zrow + k * (16 * 264));
    *(uint4*)(d) = make_uint4(zp[k][0], zp[k][1], zp[k][2], zp[k][3]);
    *(uint4*)(d + 4) = make_uint4(zp[k][4], zp[k][5], zp[k][6], zp[k][7]);
  }
}

// ---------------- MFMA: NROW k-rows, this wave's 4 K-chunks, 2 w-tiles ----------------
// B depends only on (path, chunk, wt): reused across the NROW k-rows.
template <int NROW>
__device__ __forceinline__ void mfma2(const ushort_t* zb, const ushort_t* pk,
                                      int pcbase, int h, int wt0, int lane,
                                      f32x4* accA, f32x4* accB) {
  const int srow = lane & 15, quad = lane >> 4;
  const ushort_t* ab = zb + srow * 264 + quad * 8 + h * 128;  // chunk base h*4 -> +128 ushorts
  const ushort_t* bb = pk + ((size_t)((pcbase + h * 4) * 4 + wt0) * 64 + lane) * 8;
  __builtin_amdgcn_s_setprio(1);
#pragma unroll
  for (int c = 0; c < 4; ++c) {
    short8 B0 = *(const short8*)(bb + (size_t)c * 2048);
    short8 B1 = *(const short8*)(bb + (size_t)c * 2048 + 512);
#pragma unroll
    for (int rt = 0; rt < NROW; ++rt) {
      short8 A = *(const short8*)(ab + rt * (16 * 264) + c * 32);
      accA[rt] = __builtin_amdgcn_mfma_f32_16x16x32_bf16(A, B0, accA[rt], 0, 0, 0);
      accB[rt] = __builtin_amdgcn_mfma_f32_16x16x32_bf16(A, B1, accB[rt], 0, 0, 0);
    }
  }
  __builtin_amdgcn_s_setprio(0);
}

#define ZB 12672  // one ping-pong buffer: 3 slots x 16 rows x 264 ushorts

// ---------------- main fused kernel ----------------
__global__ __launch_bounds__(256, 2) void tdense_kernel(
    const float* __restrict__ x0, const float* __restrict__ x1,
    const float* __restrict__ x2, const float* __restrict__ W10,
    const float* __restrict__ W20, const float* __restrict__ W11,
    const float* __restrict__ W21, const float* __restrict__ W12,
    const float* __restrict__ W22, const ushort_t* __restrict__ pack,
    float* __restrict__ out) {
  __shared__ float b_s[2368];                        // 9.25 KB
  __shared__ __align__(16) ushort_t zbuf[2 * ZB];    // 50.7 KB (2 buffers x 3 slots)

  const int tid = threadIdx.x;
  const int nbase = blockIdx.x * 16;
  const int s = tid >> 4, v = tid & 15;

  // ---- Phase 0: both branch linears; a stays in registers (wave-local b_s) ----
  const int n = nbase + s;
  const float* px0 = x0 + (size_t)n * 64;
  const float* px1 = x1 + (size_t)n * 192;
  const float* px2 = x2 + (size_t)n * 320;
  float a0 = 0.f, a1x = 0.f, a1y = 0.f, a1z = 0.f;
  float a2[5] = {0.f, 0.f, 0.f, 0.f, 0.f};
  float b0 = 0.f, b1x = 0.f, b1y = 0.f, b1z = 0.f;
  float b2[5] = {0.f, 0.f, 0.f, 0.f, 0.f};
  for (int u4 = 0; u4 < 16; ++u4) {
    f4 xv0 = *(const f4*)(px0 + u4 * 4);
    f4 xa = *(const f4*)(px1 + u4 * 12);
    f4 xb = *(const f4*)(px1 + u4 * 12 + 4);
    f4 xc = *(const f4*)(px1 + u4 * 12 + 8);
    f4 ya = *(const f4*)(px2 + u4 * 20);
    f4 yb = *(const f4*)(px2 + u4 * 20 + 4);
    f4 yc = *(const f4*)(px2 + u4 * 20 + 8);
    f4 yd = *(const f4*)(px2 + u4 * 20 + 12);
    f4 ye = *(const f4*)(px2 + u4 * 20 + 16);
    float x1e[12], x2e[20];
#pragma unroll
    for (int e = 0; e < 4; ++e) { x1e[e] = xa[e]; x1e[4 + e] = xb[e]; x1e[8 + e] = xc[e]; }
#pragma unroll
    for (int e = 0; e < 4; ++e) {
      x2e[e] = ya[e]; x2e[4 + e] = yb[e]; x2e[8 + e] = yc[e];
      x2e[12 + e] = yd[e]; x2e[16 + e] = ye[e];
    }
#pragma unroll
    for (int r = 0; r < 4; ++r) {
      int u = u4 * 4 + r;
      float wa0 = W10[u * 16 + v], wb0 = W20[u * 16 + v];
      float wa1 = W11[u * 16 + v], wb1 = W21[u * 16 + v];
      float wa2 = W12[u * 16 + v], wb2 = W22[u * 16 + v];
      float xx = xv0[r];
      a0 += xx * wa0; b0 += xx * wb0;
      float e0 = x1e[r * 3 + 0], e1 = x1e[r * 3 + 1], e2 = x1e[r * 3 + 2];
      a1x += e0 * wa1; a1y += e1 * wa1; a1z += e2 * wa1;
      b1x += e0 * wb1; b1y += e1 * wb1; b1z += e2 * wb1;
#pragma unroll
      for (int j = 0; j < 5; ++j) {
        float ev = x2e[r * 5 + j];
        a2[j] += ev * wa2;
        b2[j] += ev * wb2;
      }
    }
  }
  const float inv8 = 0.125f;
  float ar[9];
  ar[0] = a0 * inv8;
  ar[1] = a1x * inv8; ar[2] = a1y * inv8; ar[3] = a1z * inv8;
#pragma unroll
  for (int j = 0; j < 5; ++j) ar[4 + j] = a2[j] * inv8;
  {
    float* bw = b_s + s * 148 + v;
    bw[0] = b0 * inv8;
    bw[16] = b1x * inv8; bw[32] = b1y * inv8; bw[48] = b1z * inv8;
#pragma unroll
    for (int j = 0; j < 5; ++j) bw[64 + j * 16] = b2[j] * inv8;
  }

  const int lane = tid & 63;
  const int wv = tid >> 6;
  const int p2 = (wv & 1) * 2;  // wt0: wave's first w-tile
  const int h = wv >> 1;        // K-half: chunks h*4..h*4+3

  f32x4 aA0, aB0, aA1[3], aB1[3], aA2[5], aB2[5];
  aA0 = (f32x4)(0.f); aB0 = (f32x4)(0.f);
#pragma unroll
  for (int i = 0; i < 3; ++i) { aA1[i] = (f32x4)(0.f); aB1[i] = (f32x4)(0.f); }
#pragma unroll
  for (int i = 0; i < 5; ++i) { aA2[i] = (f32x4)(0.f); aB2[i] = (f32x4)(0.f); }

  const float* bsl0 = b_s + s * 148;
  const float* bsl1 = bsl0 + 16;
  const float* bsl2 = bsl0 + 64;
  ushort_t* z0 = zbuf + s * 264 + v * 16;  // buf0, slot0 row for this thread
  ushort_t* z1 = z0 + ZB;                  // buf1
  const ushort_t* Zb0 = zbuf;
  const ushort_t* Zb1 = zbuf + ZB;

  // ---- R0 zgen -> buf0: p0(000)@slot0/pc0, p4(110)@slot1/pc8, p12(220)@slot2/pc16
  zgenv<1, 1>(bsl0, z0, [&](const f2* b, f2* z) { z[0] = ar[0] * b[0]; });
  zgenv<1, 3>(bsl1, z0 + 4224, [&](const f2* b, f2* z) {
    z[0] = -C3 * (ar[1] * b[0] + ar[2] * b[1] + ar[3] * b[2]);
  });
  zgenv<1, 5>(bsl2, z0 + 8448, [&](const f2* b, f2* z) {
    z[0] = C5 * (ar[4] * b[0] + ar[5] * b[1] + ar[6] * b[2] + ar[7] * b[3] + ar[8] * b[4]);
  });
  __syncthreads();

  // r=0: zgen R1 (p1(011) NK3) -> buf1 ; mfma R0 (buf0, acc0)
  zgenv<3, 3>(bsl1, z1, [&](const f2* b, f2* z) {
    z[0] = ar[0] * b[0]; z[1] = ar[0] * b[1]; z[2] = ar[0] * b[2];
  });
  mfma2<1>(Zb0, pack, 0, h, p2, lane, &aA0, &aB0);
  mfma2<1>(Zb0 + 4224, pack, 8, h, p2, lane, &aA0, &aB0);
  mfma2<1>(Zb0 + 8448, pack, 16, h, p2, lane, &aA0, &aB0);
  __syncthreads();

  // r=1: zgen R2 (p3(101)) -> buf0 ; mfma R1 (buf1, pc24, acc1)
  zgenv<3, 1>(bsl0, z0, [&](const f2* b, f2* z) {
    z[0] = ar[1] * b[0]; z[1] = ar[2] * b[0]; z[2] = ar[3] * b[0];
  });
  mfma2<3>(Zb1, pack, 24, h, p2, lane, aA1, aB1);
  __syncthreads();

  // r=2: zgen R3 (p5(111)) -> buf1 ; mfma R2 (buf0, pc32)
  zgenv<3, 3>(bsl1, z1, [&](const f2* b, f2* z) {
    z[0] = C2 * (ar[2] * b[2] - ar[3] * b[1]);
    z[1] = C2 * (ar[3] * b[0] - ar[1] * b[2]);
    z[2] = C2 * (ar[1] * b[1] - ar[2] * b[0]);
  });
  mfma2<3>(Zb0, pack, 32, h, p2, lane, aA1, aB1);
  __syncthreads();

  // r=3: zgen R4 (p7(121)) -> buf0 ; mfma R3 (buf1, pc40)
  zgenv<3, 5>(bsl2, z0, [&](const f2* b, f2* z) {
    z[0] = -C310 * ar[2] * b[1] + C10 * ar[1] * b[2] - C310 * ar[3] * b[0] + C310 * ar[1] * b[4];
    z[1] = -C210 * ar[2] * b[2] - C310 * ar[3] * b[3] - C310 * ar[1] * b[1];
    z[2] = -C310 * ar[2] * b[3] + C10 * ar[3] * b[2] - C310 * ar[1] * b[0] - C310 * ar[3] * b[4];
  });
  mfma2<3>(Zb1, pack, 40, h, p2, lane, aA1, aB1);
  __syncthreads();

  // r=4: zgen R5 (p10(211)) -> buf1 ; mfma R4 (buf0, pc48)
  zgenv<3, 3>(bsl1, z1, [&](const f2* b, f2* z) {
    z[0] = -C310 * ar[5] * b[1] + C10 * ar[6] * b[0] - C310 * ar[4] * b[2] + C310 * ar[8] * b[0];
    z[1] = -C210 * ar[6] * b[1] - C310 * ar[7] * b[2] - C310 * ar[5] * b[0];
    z[2] = -C310 * ar[7] * b[1] + C10 * ar[6] * b[2] - C310 * ar[4] * b[0] - C310 * ar[8] * b[2];
  });
  mfma2<3>(Zb0, pack, 48, h, p2, lane, aA1, aB1);
  __syncthreads();

  // r=5: zgen R6 (p13(221)) -> buf0 ; mfma R5 (buf1, pc56)
  zgenv<3, 5>(bsl2, z0, [&](const f2* b, f2* z) {
    z[0] = C10 * (ar[8] * b[3] - ar[7] * b[4] + ar[4] * b[1] - ar[5] * b[0]) +
           C310 * (ar[7] * b[2] - ar[6] * b[3]);
    z[1] = C10 * (ar[5] * b[3] - ar[7] * b[1]) + C210 * (ar[4] * b[4] - ar[8] * b[0]);
    z[2] = C10 * (ar[8] * b[1] - ar[5] * b[4] + ar[7] * b[0] - ar[4] * b[3]) +
           C310 * (ar[6] * b[1] - ar[5] * b[2]);
  });
  mfma2<3>(Zb1, pack, 56, h, p2, lane, aA1, aB1);
  __syncthreads();

  // r=6: zgen R7 (p2(022) rows 0-2) -> buf1 ; mfma R6 (buf0, pc64)
  zgenv<3, 5>(bsl2, z1, [&](const f2* b, f2* z) {
    z[0] = ar[0] * b[0]; z[1] = ar[0] * b[1]; z[2] = ar[0] * b[2];
  });
  mfma2<3>(Zb0, pack, 64, h, p2, lane, aA1, aB1);
  __syncthreads();

  // r=7: zgen R8 (p2 rows 3-4) -> buf0 ; mfma R7 (buf1, pc72, acc2[0..2])
  zgenv<2, 5>(bsl2, z0, [&](const f2* b, f2* z) {
    z[0] = ar[0] * b[3]; z[1] = ar[0] * b[4];
  });
  mfma2<3>(Zb1, pack, 72, h, p2, lane, aA2, aB2);
  __syncthreads();

  // r=8: zgen R9 (p6(112) rows 0-2) -> buf1 ; mfma R8 (buf0, pc72, acc2[3..4])
  zgenv<3, 3>(bsl1, z1, [&](const f2* b, f2* z) {
    z[0] = C2 * (ar[1] * b[2] + ar[3] * b[0]);
    z[1] = C2 * (ar[2] * b[0] + ar[1] * b[1]);
    z[2] = C23 * ar[2] * b[1] - C6 * (ar[1] * b[0] + ar[3] * b[2]);
  });
  mfma2<2>(Zb0, pack, 72, h, p2, lane, aA2 + 3, aB2 + 3);
  __syncthreads();

  // r=9: zgen R10 (p6 rows 3-4) -> buf0 ; mfma R9 (buf1, pc80, acc2[0..2])
  zgenv<2, 3>(bsl1, z0, [&](const f2* b, f2* z) {
    z[0] = C2 * (ar[2] * b[2] + ar[3] * b[1]);
    z[1] = C2 * (ar[3] * b[2] - ar[1] * b[0]);
  });
  mfma2<3>(Zb1, pack, 80, h, p2, lane, aA2, aB2);
  __syncthreads();

  // r=10: zgen R11 (p8(122) rows 0-2) -> buf1 ; mfma R10 (buf0, pc80, acc2[3..4])
  zgenv<3, 5>(bsl2, z1, [&](const f2* b, f2* z) {
    z[0] = C23 * ar[2] * b[4] + C6 * ar[1] * b[1] - C6 * ar[3] * b[3];
    z[1] = C6 * ar[2] * b[3] - C6 * ar[1] * b[0] - C2 * ar[3] * b[2] - C6 * ar[3] * b[4];
    z[2] = C2 * (ar[3] * b[1] - ar[1] * b[3]);
  });
  mfma2<2>(Zb0, pack, 80, h, p2, lane, aA2 + 3, aB2 + 3);
  __syncthreads();

  // r=11: zgen R12 (p8 rows 3-4) -> buf0 ; mfma R11 (buf1, pc88, acc2[0..2])
  zgenv<2, 5>(bsl2, z0, [&](const f2* b, f2* z) {
    z[0] = -C6 * ar[2] * b[1] + C2 * ar[1] * b[2] + C6 * ar[3] * b[0] - C6 * ar[1] * b[4];
    z[1] = -C23 * ar[2] * b[0] + C6 * ar[1] * b[3] + C6 * ar[3] * b[1];
  });
  mfma2<3>(Zb1, pack, 88, h, p2, lane, aA2, aB2);
  __syncthreads();

  // r=12: zgen R13 (p9(202) rows 0-2) -> buf1 ; mfma R12 (buf0, pc88, acc2[3..4])
  zgenv<3, 1>(bsl0, z1, [&](const f2* b, f2* z) {
    z[0] = ar[4] * b[0]; z[1] = ar[5] * b[0]; z[2] = ar[6] * b[0];
  });
  mfma2<2>(Zb0, pack, 88, h, p2, lane, aA2 + 3, aB2 + 3);
  __syncthreads();

  // r=13: zgen R14 (p9 rows 3-4) -> buf0 ; mfma R13 (buf1, pc96, acc2[0..2])
  zgenv<2, 1>(bsl0, z0, [&](const f2* b, f2* z) {
    z[0] = ar[7] * b[0]; z[1] = ar[8] * b[0];
  });
  mfma2<3>(Zb1, pack, 96, h, p2, lane, aA2, aB2);
  __syncthreads();

  // r=14: zgen R15 (p11(212) rows 0-2) -> buf1 ; mfma R14 (buf0, pc96, acc2[3..4])
  zgenv<3, 3>(bsl1, z1, [&](const f2* b, f2* z) {
    z[0] = -C23 * ar[8] * b[1] - C6 * ar[5] * b[0] + C6 * ar[7] * b[2];
    z[1] = -C6 * ar[7] * b[1] + C6 * ar[4] * b[0] + C2 * ar[6] * b[2] + C6 * ar[8] * b[2];
    z[2] = C2 * (ar[7] * b[0] - ar[5] * b[2]);
  });
  mfma2<2>(Zb0, pack, 96, h, p2, lane, aA2 + 3, aB2 + 3);
  __syncthreads();

  // r=15: zgen R16 (p11 rows 3-4) -> buf0 ; mfma R15 (buf1, pc104, acc2[0..2])
  zgenv<2, 3>(bsl1, z0, [&](const f2* b, f2* z) {
    z[0] = C6 * ar[5] * b[1] - C2 * ar[6] * b[0] - C6 * ar[4] * b[2] + C6 * ar[8] * b[0];
    z[1] = C23 * ar[4] * b[1] - C6 * ar[7] * b[0] - C6 * ar[5] * b[2];
  });
  mfma2<3>(Zb1, pack, 104, h, p2, lane, aA2, aB2);
  __syncthreads();

  // r=16: zgen R17 (p14(222) rows 0-2) -> buf1 ; mfma R16 (buf0, pc104, acc2[3..4])
  zgenv<3, 5>(bsl2, z1, [&](const f2* b, f2* z) {
    z[0] = C214 * (ar[6] * b[0] + ar[4] * b[2]) - C314 * (ar[5] * b[3] + ar[7] * b[1]);
    z[1] = -C14 * (ar[6] * b[1] + ar[5] * b[2]) + C314 * (ar[5] * b[4] + ar[8] * b[1]) -
           C314 * (ar[7] * b[0] + ar[4] * b[3]);
    z[2] = -C214 * ar[6] * b[2] - C14 * (ar[5] * b[1] + ar[7] * b[3]) +
           C214 * (ar[4] * b[0] + ar[8] * b[4]);
  });
  mfma2<2>(Zb0, pack, 104, h, p2, lane, aA2 + 3, aB2 + 3);
  __syncthreads();

  // r=17: zgen R18 (p14 rows 3-4) -> buf0 ; mfma R17 (buf1, pc112, acc2[0..2])
  zgenv<2, 5>(bsl2, z0, [&](const f2* b, f2* z) {
    z[0] = -C14 * (ar[6] * b[3] + ar[7] * b[2]) - C314 * (ar[5] * b[0] + ar[4] * b[1]) -
           C314 * (ar[7] * b[4] + ar[8] * b[3]);
    z[1] = C214 * (ar[6] * b[4] + ar[8] * b[2]) + C314 * (ar[5] * b[1] - ar[7] * b[3]);
  });
  mfma2<3>(Zb1, pack, 112, h, p2, lane, aA2, aB2);
  __syncthreads();

  // r=18: mfma R18 (buf0, pc112, acc2[3..4])
  mfma2<2>(Zb0, pack, 112, h, p2, lane, aA2 + 3, aB2 + 3);
  __syncthreads();  // all reads of zbuf done before reduction overwrites it

  // ---- Cross-wave K-half reduction via LDS, then global store (h==1 waves) ----
  float* red = (float*)zbuf;
  const int col = lane & 15, quad = lane >> 4;
  if (h == 0) {
#pragma unroll
    for (int pp = 0; pp < 2; ++pp) {
      int wt = p2 + pp;
      const f32x4* src0 = pp ? &aB0 : &aA0;
      const f32x4* src1 = pp ? aB1 : aA1;
      const f32x4* src2 = pp ? aB2 : aA2;
      *(f4*)(red + (wt * 9 + 0) * 256 + lane * 4) = src0[0];
#pragma unroll
      for (int o = 0; o < 3; ++o)
        *(f4*)(red + (wt * 9 + 1 + o) * 256 + lane * 4) = src1[o];
#pragma unroll
      for (int o = 0; o < 5; ++o)
        *(f4*)(red + (wt * 9 + 4 + o) * 256 + lane * 4) = src2[o];
    }
  }
  __syncthreads();
  if (h == 1) {
    aA0 += *(const f4*)(red + (p2 * 9 + 0) * 256 + lane * 4);
    aB0 += *(const f4*)(red + ((p2 + 1) * 9 + 0) * 256 + lane * 4);
#pragma unroll
    for (int o = 0; o < 3; ++o) {
      aA1[o] += *(const f4*)(red + (p2 * 9 + 1 + o) * 256 + lane * 4);
      aB1[o] += *(const f4*)(red + ((p2 + 1) * 9 + 1 + o) * 256 + lane * 4);
    }
#pragma unroll
    for (int o = 0; o < 5; ++o) {
      aA2[o] += *(const f4*)(red + (p2 * 9 + 4 + o) * 256 + lane * 4);
      aB2[o] += *(const f4*)(red + ((p2 + 1) * 9 + 4 + o) * 256 + lane * 4);
    }
    const int w0 = p2 * 16 + col, w1 = w0 + 16;
#pragma unroll
    for (int r = 0; r < 4; ++r) {
      int so = quad * 4 + r;
      float* row = out + (size_t)(nbase + so) * 576;
      row[w0] = aA0[r];
      row[w1] = aB0[r];
      row[64 + w0 * 3 + 0] = aA1[0][r];
      row[64 + w0 * 3 + 1] = aA1[1][r];
      row[64 + w0 * 3 + 2] = aA1[2][r];
      row[64 + w1 * 3 + 0] = aB1[0][r];
      row[64 + w1 * 3 + 1] = aB1[1][r];
      row[64 + w1 * 3 + 2] = aB1[2][r];
#pragma unroll
      for (int k = 0; k < 5; ++k) {
        row[256 + w0 * 5 + k] = aA2[k][r];
        row[256 + w1 * 5 + k] = aB2[k][r];
      }
    }
  }
}

extern "C" void kernel_launch(void* const* d_in, const int* in_sizes, int n_in,
                              void* d_out, int out_size, void* d_ws, size_t ws_size,
                              hipStream_t stream) {
  const float* x0 = (const float*)d_in[0];
  const float* x1 = (const float*)d_in[1];
  const float* x2 = (const float*)d_in[2];
  const float* W10 = (const float*)d_in[3];
  const float* W20 = (const float*)d_in[4];
  const float* W11 = (const float*)d_in[5];
  const float* W21 = (const float*)d_in[6];
  const float* W12 = (const float*)d_in[7];
  const float* W22 = (const float*)d_in[8];
  const float* W30 = (const float*)d_in[9];
  const float* W31 = (const float*)d_in[10];
  const float* W32 = (const float*)d_in[11];
  ushort_t* pack = (ushort_t*)d_ws;  // 491,520 bytes used

  hipLaunchKernelGGL(pack_w3_kernel, dim3(120), dim3(256), 0, stream,
                     W30, W31, W32, pack);

  int nsamp = in_sizes[0] / 64;  // 20000
  int nblocks = nsamp / 16;      // 1250
  hipLaunchKernelGGL(tdense_kernel, dim3(nblocks), dim3(256), 0, stream,
                     x0, x1, x2, W10, W20, W11, W21, W12, W22, pack,
                     (float*)d_out);
}

// Round 9
// 221.481 us; speedup vs baseline: 2.6649x; 1.0170x over previous
//
#include <hip/hip_runtime.h>

// R12 = exact revert to R3 (harness-verified best: 218.9 us session metric,
// ~138 us/dispatch). Setprio A/B (R11) measured +3% -> reverted per discipline
// (lockstep 4-wave barrier structure has no role diversity; m190-class null).
// R3: K-split x w-pair wave tiling (each wave: 2 w-tiles x 4 of 8 K-chunks ->
// A-frag LDS reads halved, 2 MFMAs per A read), ping-pong z buffers with ONE
// barrier per round (19 rounds; NK5 paths split 3+2 rows) so zgen VALU, LDS
// A-reads and MFMA co-issue. Cross-wave (h=0/h=1) accumulator reduction via LDS.

typedef __attribute__((ext_vector_type(4))) float f32x4;
typedef __attribute__((ext_vector_type(4))) float f4;
typedef __attribute__((ext_vector_type(2))) float f2;
typedef __attribute__((ext_vector_type(8))) short short8;
typedef unsigned short ushort_t;
typedef unsigned int uint32;

__device__ __forceinline__ uint32 bfb(float x) {
  uint32 u = __float_as_uint(x);
  return (u + 0x7fffu + ((u >> 16) & 1u)) >> 16;  // RNE fp32->bf16 (pack kernel)
}
// round-half-away pack of 2 fp32 -> packed bf16x2: 2 adds + 1 v_perm
__device__ __forceinline__ uint32 pack2f(f2 z) {
  uint32 lo = __float_as_uint(z.x) + 0x8000u;
  uint32 hi = __float_as_uint(z.y) + 0x8000u;
  return __builtin_amdgcn_perm(hi, lo, 0x07060302u);
}

#define C2   0.7071067811865476f
#define C3   0.5773502691896258f
#define C5   0.4472135954999579f
#define C6   0.4082482904638631f
#define C23  0.8164965809277260f
#define C10  0.3162277660168379f
#define C210 0.6324555320336759f
#define C310 0.5477225575051661f
#define C14  0.2672612419124244f
#define C214 0.5345224838248488f
#define C314 0.4629100498862757f

// ---------------- W3 pre-pack: B-fragment order, bf16, norm folded ----------------
__global__ __launch_bounds__(256) void pack_w3_kernel(
    const float* __restrict__ W30, const float* __restrict__ W31,
    const float* __restrict__ W32, ushort_t* __restrict__ pack) {
  int lc = blockIdx.x;
  int t = threadIdx.x >> 6;
  int lam = threadIdx.x & 63;
  const float* W;
  int mb;
  float nrm;
  if (lc < 24) {
    W = W30; mb = lc * 32; nrm = 0.036084391824351615f;        // 1/sqrt(768)
  } else if (lc < 72) {
    W = W31; mb = (lc - 24) * 32; nrm = 0.025515518153991442f; // 1/sqrt(1536)
  } else {
    W = W32; mb = (lc - 72) * 32; nrm = 0.025515518153991442f;
  }
  int w = t * 16 + (lam & 15);
  int m0 = mb + (lam >> 4) * 8;
  ushort_t* dst = pack + ((size_t)(lc * 4 + t) * 64 + lam) * 8;
#pragma unroll
  for (int j = 0; j < 8; ++j)
    dst[j] = (ushort_t)bfb(W[(size_t)(m0 + j) * 64 + w] * nrm);
}

// ---------------- z generation (unchanged from R2) ----------------
// b_s: [s][9 jslots][16 v] floats, s-stride 148 (20 mod 32 -> conflict-free bcast)
template <int NK, int JD, class F>
__device__ __forceinline__ void zgenv(const float* bsj, ushort_t* zrow, F f) {
  uint32 zp[NK][8];
#pragma unroll
  for (int oc = 0; oc < 2; ++oc) {
    f2 bb4[JD][4];
#pragma unroll
    for (int j = 0; j < JD; ++j) {
      f4 lo = *(const f4*)(bsj + j * 16 + oc * 8);
      f4 hi = *(const f4*)(bsj + j * 16 + oc * 8 + 4);
      bb4[j][0] = lo.xy; bb4[j][1] = lo.zw;
      bb4[j][2] = hi.xy; bb4[j][3] = hi.zw;
    }
#pragma unroll
    for (int q = 0; q < 4; ++q) {
      f2 bcol[JD], z[NK];
#pragma unroll
      for (int j = 0; j < JD; ++j) bcol[j] = bb4[j][q];
      f(bcol, z);
#pragma unroll
      for (int k = 0; k < NK; ++k) zp[k][oc * 4 + q] = pack2f(z[k]);
    }
  }
#pragma unroll
  for (int k = 0; k < NK; ++k) {
    uint32* d = (uint32*)(zrow + k * (16 * 264));
    *(uint4*)(d) = make_uint4(zp[k][0], zp[k][1], zp[k][2], zp[k][3]);
    *(uint4*)(d + 4) = make_uint4(zp[k][4], zp[k][5], zp[k][6], zp[k][7]);
  }
}

// ---------------- MFMA: NROW k-rows, this wave's 4 K-chunks, 2 w-tiles ----------------
// B depends only on (path, chunk, wt): reused across the NROW k-rows.
template <int NROW>
__device__ __forceinline__ void mfma2(const ushort_t* zb, const ushort_t* pk,
                                      int pcbase, int h, int wt0, int lane,
                                      f32x4* accA, f32x4* accB) {
  const int srow = lane & 15, quad = lane >> 4;
  const ushort_t* ab = zb + srow * 264 + quad * 8 + h * 128;  // chunk base h*4 -> +128 ushorts
  const ushort_t* bb = pk + ((size_t)((pcbase + h * 4) * 4 + wt0) * 64 + lane) * 8;
#pragma unroll
  for (int c = 0; c < 4; ++c) {
    short8 B0 = *(const short8*)(bb + (size_t)c * 2048);
    short8 B1 = *(const short8*)(bb + (size_t)c * 2048 + 512);
#pragma unroll
    for (int rt = 0; rt < NROW; ++rt) {
      short8 A = *(const short8*)(ab + rt * (16 * 264) + c * 32);
      accA[rt] = __builtin_amdgcn_mfma_f32_16x16x32_bf16(A, B0, accA[rt], 0, 0, 0);
      accB[rt] = __builtin_amdgcn_mfma_f32_16x16x32_bf16(A, B1, accB[rt], 0, 0, 0);
    }
  }
}

#define ZB 12672  // one ping-pong buffer: 3 slots x 16 rows x 264 ushorts

// ---------------- main fused kernel ----------------
__global__ __launch_bounds__(256, 2) void tdense_kernel(
    const float* __restrict__ x0, const float* __restrict__ x1,
    const float* __restrict__ x2, const float* __restrict__ W10,
    const float* __restrict__ W20, const float* __restrict__ W11,
    const float* __restrict__ W21, const float* __restrict__ W12,
    const float* __restrict__ W22, const ushort_t* __restrict__ pack,
    float* __restrict__ out) {
  __shared__ float b_s[2368];                        // 9.25 KB
  __shared__ __align__(16) ushort_t zbuf[2 * ZB];    // 50.7 KB (2 buffers x 3 slots)

  const int tid = threadIdx.x;
  const int nbase = blockIdx.x * 16;
  const int s = tid >> 4, v = tid & 15;

  // ---- Phase 0: both branch linears; a stays in registers (wave-local b_s) ----
  const int n = nbase + s;
  const float* px0 = x0 + (size_t)n * 64;
  const float* px1 = x1 + (size_t)n * 192;
  const float* px2 = x2 + (size_t)n * 320;
  float a0 = 0.f, a1x = 0.f, a1y = 0.f, a1z = 0.f;
  float a2[5] = {0.f, 0.f, 0.f, 0.f, 0.f};
  float b0 = 0.f, b1x = 0.f, b1y = 0.f, b1z = 0.f;
  float b2[5] = {0.f, 0.f, 0.f, 0.f, 0.f};
  for (int u4 = 0; u4 < 16; ++u4) {
    f4 xv0 = *(const f4*)(px0 + u4 * 4);
    f4 xa = *(const f4*)(px1 + u4 * 12);
    f4 xb = *(const f4*)(px1 + u4 * 12 + 4);
    f4 xc = *(const f4*)(px1 + u4 * 12 + 8);
    f4 ya = *(const f4*)(px2 + u4 * 20);
    f4 yb = *(const f4*)(px2 + u4 * 20 + 4);
    f4 yc = *(const f4*)(px2 + u4 * 20 + 8);
    f4 yd = *(const f4*)(px2 + u4 * 20 + 12);
    f4 ye = *(const f4*)(px2 + u4 * 20 + 16);
    float x1e[12], x2e[20];
#pragma unroll
    for (int e = 0; e < 4; ++e) { x1e[e] = xa[e]; x1e[4 + e] = xb[e]; x1e[8 + e] = xc[e]; }
#pragma unroll
    for (int e = 0; e < 4; ++e) {
      x2e[e] = ya[e]; x2e[4 + e] = yb[e]; x2e[8 + e] = yc[e];
      x2e[12 + e] = yd[e]; x2e[16 + e] = ye[e];
    }
#pragma unroll
    for (int r = 0; r < 4; ++r) {
      int u = u4 * 4 + r;
      float wa0 = W10[u * 16 + v], wb0 = W20[u * 16 + v];
      float wa1 = W11[u * 16 + v], wb1 = W21[u * 16 + v];
      float wa2 = W12[u * 16 + v], wb2 = W22[u * 16 + v];
      float xx = xv0[r];
      a0 += xx * wa0; b0 += xx * wb0;
      float e0 = x1e[r * 3 + 0], e1 = x1e[r * 3 + 1], e2 = x1e[r * 3 + 2];
      a1x += e0 * wa1; a1y += e1 * wa1; a1z += e2 * wa1;
      b1x += e0 * wb1; b1y += e1 * wb1; b1z += e2 * wb1;
#pragma unroll
      for (int j = 0; j < 5; ++j) {
        float ev = x2e[r * 5 + j];
        a2[j] += ev * wa2;
        b2[j] += ev * wb2;
      }
    }
  }
  const float inv8 = 0.125f;
  float ar[9];
  ar[0] = a0 * inv8;
  ar[1] = a1x * inv8; ar[2] = a1y * inv8; ar[3] = a1z * inv8;
#pragma unroll
  for (int j = 0; j < 5; ++j) ar[4 + j] = a2[j] * inv8;
  {
    float* bw = b_s + s * 148 + v;
    bw[0] = b0 * inv8;
    bw[16] = b1x * inv8; bw[32] = b1y * inv8; bw[48] = b1z * inv8;
#pragma unroll
    for (int j = 0; j < 5; ++j) bw[64 + j * 16] = b2[j] * inv8;
  }

  const int lane = tid & 63;
  const int wv = tid >> 6;
  const int p2 = (wv & 1) * 2;  // wt0: wave's first w-tile
  const int h = wv >> 1;        // K-half: chunks h*4..h*4+3

  f32x4 aA0, aB0, aA1[3], aB1[3], aA2[5], aB2[5];
  aA0 = (f32x4)(0.f); aB0 = (f32x4)(0.f);
#pragma unroll
  for (int i = 0; i < 3; ++i) { aA1[i] = (f32x4)(0.f); aB1[i] = (f32x4)(0.f); }
#pragma unroll
  for (int i = 0; i < 5; ++i) { aA2[i] = (f32x4)(0.f); aB2[i] = (f32x4)(0.f); }

  const float* bsl0 = b_s + s * 148;
  const float* bsl1 = bsl0 + 16;
  const float* bsl2 = bsl0 + 64;
  ushort_t* z0 = zbuf + s * 264 + v * 16;  // buf0, slot0 row for this thread
  ushort_t* z1 = z0 + ZB;                  // buf1
  const ushort_t* Zb0 = zbuf;
  const ushort_t* Zb1 = zbuf + ZB;

  // ---- R0 zgen -> buf0: p0(000)@slot0/pc0, p4(110)@slot1/pc8, p12(220)@slot2/pc16
  zgenv<1, 1>(bsl0, z0, [&](const f2* b, f2* z) { z[0] = ar[0] * b[0]; });
  zgenv<1, 3>(bsl1, z0 + 4224, [&](const f2* b, f2* z) {
    z[0] = -C3 * (ar[1] * b[0] + ar[2] * b[1] + ar[3] * b[2]);
  });
  zgenv<1, 5>(bsl2, z0 + 8448, [&](const f2* b, f2* z) {
    z[0] = C5 * (ar[4] * b[0] + ar[5] * b[1] + ar[6] * b[2] + ar[7] * b[3] + ar[8] * b[4]);
  });
  __syncthreads();

  // r=0: zgen R1 (p1(011) NK3) -> buf1 ; mfma R0 (buf0, acc0)
  zgenv<3, 3>(bsl1, z1, [&](const f2* b, f2* z) {
    z[0] = ar[0] * b[0]; z[1] = ar[0] * b[1]; z[2] = ar[0] * b[2];
  });
  mfma2<1>(Zb0, pack, 0, h, p2, lane, &aA0, &aB0);
  mfma2<1>(Zb0 + 4224, pack, 8, h, p2, lane, &aA0, &aB0);
  mfma2<1>(Zb0 + 8448, pack, 16, h, p2, lane, &aA0, &aB0);
  __syncthreads();

  // r=1: zgen R2 (p3(101)) -> buf0 ; mfma R1 (buf1, pc24, acc1)
  zgenv<3, 1>(bsl0, z0, [&](const f2* b, f2* z) {
    z[0] = ar[1] * b[0]; z[1] = ar[2] * b[0]; z[2] = ar[3] * b[0];
  });
  mfma2<3>(Zb1, pack, 24, h, p2, lane, aA1, aB1);
  __syncthreads();

  // r=2: zgen R3 (p5(111)) -> buf1 ; mfma R2 (buf0, pc32)
  zgenv<3, 3>(bsl1, z1, [&](const f2* b, f2* z) {
    z[0] = C2 * (ar[2] * b[2] - ar[3] * b[1]);
    z[1] = C2 * (ar[3] * b[0] - ar[1] * b[2]);
    z[2] = C2 * (ar[1] * b[1] - ar[2] * b[0]);
  });
  mfma2<3>(Zb0, pack, 32, h, p2, lane, aA1, aB1);
  __syncthreads();

  // r=3: zgen R4 (p7(121)) -> buf0 ; mfma R3 (buf1, pc40)
  zgenv<3, 5>(bsl2, z0, [&](const f2* b, f2* z) {
    z[0] = -C310 * ar[2] * b[1] + C10 * ar[1] * b[2] - C310 * ar[3] * b[0] + C310 * ar[1] * b[4];
    z[1] = -C210 * ar[2] * b[2] - C310 * ar[3] * b[3] - C310 * ar[1] * b[1];
    z[2] = -C310 * ar[2] * b[3] + C10 * ar[3] * b[2] - C310 * ar[1] * b[0] - C310 * ar[3] * b[4];
  });
  mfma2<3>(Zb1, pack, 40, h, p2, lane, aA1, aB1);
  __syncthreads();

  // r=4: zgen R5 (p10(211)) -> buf1 ; mfma R4 (buf0, pc48)
  zgenv<3, 3>(bsl1, z1, [&](const f2* b, f2* z) {
    z[0] = -C310 * ar[5] * b[1] + C10 * ar[6] * b[0] - C310 * ar[4] * b[2] + C310 * ar[8] * b[0];
    z[1] = -C210 * ar[6] * b[1] - C310 * ar[7] * b[2] - C310 * ar[5] * b[0];
    z[2] = -C310 * ar[7] * b[1] + C10 * ar[6] * b[2] - C310 * ar[4] * b[0] - C310 * ar[8] * b[2];
  });
  mfma2<3>(Zb0, pack, 48, h, p2, lane, aA1, aB1);
  __syncthreads();

  // r=5: zgen R6 (p13(221)) -> buf0 ; mfma R5 (buf1, pc56)
  zgenv<3, 5>(bsl2, z0, [&](const f2* b, f2* z) {
    z[0] = C10 * (ar[8] * b[3] - ar[7] * b[4] + ar[4] * b[1] - ar[5] * b[0]) +
           C310 * (ar[7] * b[2] - ar[6] * b[3]);
    z[1] = C10 * (ar[5] * b[3] - ar[7] * b[1]) + C210 * (ar[4] * b[4] - ar[8] * b[0]);
    z[2] = C10 * (ar[8] * b[1] - ar[5] * b[4] + ar[7] * b[0] - ar[4] * b[3]) +
           C310 * (ar[6] * b[1] - ar[5] * b[2]);
  });
  mfma2<3>(Zb1, pack, 56, h, p2, lane, aA1, aB1);
  __syncthreads();

  // r=6: zgen R7 (p2(022) rows 0-2) -> buf1 ; mfma R6 (buf0, pc64)
  zgenv<3, 5>(bsl2, z1, [&](const f2* b, f2* z) {
    z[0] = ar[0] * b[0]; z[1] = ar[0] * b[1]; z[2] = ar[0] * b[2];
  });
  mfma2<3>(Zb0, pack, 64, h, p2, lane, aA1, aB1);
  __syncthreads();

  // r=7: zgen R8 (p2 rows 3-4) -> buf0 ; mfma R7 (buf1, pc72, acc2[0..2])
  zgenv<2, 5>(bsl2, z0, [&](const f2* b, f2* z) {
    z[0] = ar[0] * b[3]; z[1] = ar[0] * b[4];
  });
  mfma2<3>(Zb1, pack, 72, h, p2, lane, aA2, aB2);
  __syncthreads();

  // r=8: zgen R9 (p6(112) rows 0-2) -> buf1 ; mfma R8 (buf0, pc72, acc2[3..4])
  zgenv<3, 3>(bsl1, z1, [&](const f2* b, f2* z) {
    z[0] = C2 * (ar[1] * b[2] + ar[3] * b[0]);
    z[1] = C2 * (ar[2] * b[0] + ar[1] * b[1]);
    z[2] = C23 * ar[2] * b[1] - C6 * (ar[1] * b[0] + ar[3] * b[2]);
  });
  mfma2<2>(Zb0, pack, 72, h, p2, lane, aA2 + 3, aB2 + 3);
  __syncthreads();

  // r=9: zgen R10 (p6 rows 3-4) -> buf0 ; mfma R9 (buf1, pc80, acc2[0..2])
  zgenv<2, 3>(bsl1, z0, [&](const f2* b, f2* z) {
    z[0] = C2 * (ar[2] * b[2] + ar[3] * b[1]);
    z[1] = C2 * (ar[3] * b[2] - ar[1] * b[0]);
  });
  mfma2<3>(Zb1, pack, 80, h, p2, lane, aA2, aB2);
  __syncthreads();

  // r=10: zgen R11 (p8(122) rows 0-2) -> buf1 ; mfma R10 (buf0, pc80, acc2[3..4])
  zgenv<3, 5>(bsl2, z1, [&](const f2* b, f2* z) {
    z[0] = C23 * ar[2] * b[4] + C6 * ar[1] * b[1] - C6 * ar[3] * b[3];
    z[1] = C6 * ar[2] * b[3] - C6 * ar[1] * b[0] - C2 * ar[3] * b[2] - C6 * ar[3] * b[4];
    z[2] = C2 * (ar[3] * b[1] - ar[1] * b[3]);
  });
  mfma2<2>(Zb0, pack, 80, h, p2, lane, aA2 + 3, aB2 + 3);
  __syncthreads();

  // r=11: zgen R12 (p8 rows 3-4) -> buf0 ; mfma R11 (buf1, pc88, acc2[0..2])
  zgenv<2, 5>(bsl2, z0, [&](const f2* b, f2* z) {
    z[0] = -C6 * ar[2] * b[1] + C2 * ar[1] * b[2] + C6 * ar[3] * b[0] - C6 * ar[1] * b[4];
    z[1] = -C23 * ar[2] * b[0] + C6 * ar[1] * b[3] + C6 * ar[3] * b[1];
  });
  mfma2<3>(Zb1, pack, 88, h, p2, lane, aA2, aB2);
  __syncthreads();

  // r=12: zgen R13 (p9(202) rows 0-2) -> buf1 ; mfma R12 (buf0, pc88, acc2[3..4])
  zgenv<3, 1>(bsl0, z1, [&](const f2* b, f2* z) {
    z[0] = ar[4] * b[0]; z[1] = ar[5] * b[0]; z[2] = ar[6] * b[0];
  });
  mfma2<2>(Zb0, pack, 88, h, p2, lane, aA2 + 3, aB2 + 3);
  __syncthreads();

  // r=13: zgen R14 (p9 rows 3-4) -> buf0 ; mfma R13 (buf1, pc96, acc2[0..2])
  zgenv<2, 1>(bsl0, z0, [&](const f2* b, f2* z) {
    z[0] = ar[7] * b[0]; z[1] = ar[8] * b[0];
  });
  mfma2<3>(Zb1, pack, 96, h, p2, lane, aA2, aB2);
  __syncthreads();

  // r=14: zgen R15 (p11(212) rows 0-2) -> buf1 ; mfma R14 (buf0, pc96, acc2[3..4])
  zgenv<3, 3>(bsl1, z1, [&](const f2* b, f2* z) {
    z[0] = -C23 * ar[8] * b[1] - C6 * ar[5] * b[0] + C6 * ar[7] * b[2];
    z[1] = -C6 * ar[7] * b[1] + C6 * ar[4] * b[0] + C2 * ar[6] * b[2] + C6 * ar[8] * b[2];
    z[2] = C2 * (ar[7] * b[0] - ar[5] * b[2]);
  });
  mfma2<2>(Zb0, pack, 96, h, p2, lane, aA2 + 3, aB2 + 3);
  __syncthreads();

  // r=15: zgen R16 (p11 rows 3-4) -> buf0 ; mfma R15 (buf1, pc104, acc2[0..2])
  zgenv<2, 3>(bsl1, z0, [&](const f2* b, f2* z) {
    z[0] = C6 * ar[5] * b[1] - C2 * ar[6] * b[0] - C6 * ar[4] * b[2] + C6 * ar[8] * b[0];
    z[1] = C23 * ar[4] * b[1] - C6 * ar[7] * b[0] - C6 * ar[5] * b[2];
  });
  mfma2<3>(Zb1, pack, 104, h, p2, lane, aA2, aB2);
  __syncthreads();

  // r=16: zgen R17 (p14(222) rows 0-2) -> buf1 ; mfma R16 (buf0, pc104, acc2[3..4])
  zgenv<3, 5>(bsl2, z1, [&](const f2* b, f2* z) {
    z[0] = C214 * (ar[6] * b[0] + ar[4] * b[2]) - C314 * (ar[5] * b[3] + ar[7] * b[1]);
    z[1] = -C14 * (ar[6] * b[1] + ar[5] * b[2]) + C314 * (ar[5] * b[4] + ar[8] * b[1]) -
           C314 * (ar[7] * b[0] + ar[4] * b[3]);
    z[2] = -C214 * ar[6] * b[2] - C14 * (ar[5] * b[1] + ar[7] * b[3]) +
           C214 * (ar[4] * b[0] + ar[8] * b[4]);
  });
  mfma2<2>(Zb0, pack, 104, h, p2, lane, aA2 + 3, aB2 + 3);
  __syncthreads();

  // r=17: zgen R18 (p14 rows 3-4) -> buf0 ; mfma R17 (buf1, pc112, acc2[0..2])
  zgenv<2, 5>(bsl2, z0, [&](const f2* b, f2* z) {
    z[0] = -C14 * (ar[6] * b[3] + ar[7] * b[2]) - C314 * (ar[5] * b[0] + ar[4] * b[1]) -
           C314 * (ar[7] * b[4] + ar[8] * b[3]);
    z[1] = C214 * (ar[6] * b[4] + ar[8] * b[2]) + C314 * (ar[5] * b[1] - ar[7] * b[3]);
  });
  mfma2<3>(Zb1, pack, 112, h, p2, lane, aA2, aB2);
  __syncthreads();

  // r=18: mfma R18 (buf0, pc112, acc2[3..4])
  mfma2<2>(Zb0, pack, 112, h, p2, lane, aA2 + 3, aB2 + 3);
  __syncthreads();  // all reads of zbuf done before reduction overwrites it

  // ---- Cross-wave K-half reduction via LDS, then global store (h==1 waves) ----
  float* red = (float*)zbuf;
  const int col = lane & 15, quad = lane >> 4;
  if (h == 0) {
#pragma unroll
    for (int pp = 0; pp < 2; ++pp) {
      int wt = p2 + pp;
      const f32x4* src0 = pp ? &aB0 : &aA0;
      const f32x4* src1 = pp ? aB1 : aA1;
      const f32x4* src2 = pp ? aB2 : aA2;
      *(f4*)(red + (wt * 9 + 0) * 256 + lane * 4) = src0[0];
#pragma unroll
      for (int o = 0; o < 3; ++o)
        *(f4*)(red + (wt * 9 + 1 + o) * 256 + lane * 4) = src1[o];
#pragma unroll
      for (int o = 0; o < 5; ++o)
        *(f4*)(red + (wt * 9 + 4 + o) * 256 + lane * 4) = src2[o];
    }
  }
  __syncthreads();
  if (h == 1) {
    aA0 += *(const f4*)(red + (p2 * 9 + 0) * 256 + lane * 4);
    aB0 += *(const f4*)(red + ((p2 + 1) * 9 + 0) * 256 + lane * 4);
#pragma unroll
    for (int o = 0; o < 3; ++o) {
      aA1[o] += *(const f4*)(red + (p2 * 9 + 1 + o) * 256 + lane * 4);
      aB1[o] += *(const f4*)(red + ((p2 + 1) * 9 + 1 + o) * 256 + lane * 4);
    }
#pragma unroll
    for (int o = 0; o < 5; ++o) {
      aA2[o] += *(const f4*)(red + (p2 * 9 + 4 + o) * 256 + lane * 4);
      aB2[o] += *(const f4*)(red + ((p2 + 1) * 9 + 4 + o) * 256 + lane * 4);
    }
    const int w0 = p2 * 16 + col, w1 = w0 + 16;
#pragma unroll
    for (int r = 0; r < 4; ++r) {
      int so = quad * 4 + r;
      float* row = out + (size_t)(nbase + so) * 576;
      row[w0] = aA0[r];
      row[w1] = aB0[r];
      row[64 + w0 * 3 + 0] = aA1[0][r];
      row[64 + w0 * 3 + 1] = aA1[1][r];
      row[64 + w0 * 3 + 2] = aA1[2][r];
      row[64 + w1 * 3 + 0] = aB1[0][r];
      row[64 + w1 * 3 + 1] = aB1[1][r];
      row[64 + w1 * 3 + 2] = aB1[2][r];
#pragma unroll
      for (int k = 0; k < 5; ++k) {
        row[256 + w0 * 5 + k] = aA2[k][r];
        row[256 + w1 * 5 + k] = aB2[k][r];
      }
    }
  }
}

extern "C" void kernel_launch(void* const* d_in, const int* in_sizes, int n_in,
                              void* d_out, int out_size, void* d_ws, size_t ws_size,
                              hipStream_t stream) {
  const float* x0 = (const float*)d_in[0];
  const float* x1 = (const float*)d_in[1];
  const float* x2 = (const float*)d_in[2];
  const float* W10 = (const float*)d_in[3];
  const float* W20 = (const float*)d_in[4];
  const float* W11 = (const float*)d_in[5];
  const float* W21 = (const float*)d_in[6];
  const float* W12 = (const float*)d_in[7];
  const float* W22 = (const float*)d_in[8];
  const float* W30 = (const float*)d_in[9];
  const float* W31 = (const float*)d_in[10];
  const float* W32 = (const float*)d_in[11];
  ushort_t* pack = (ushort_t*)d_ws;  // 491,520 bytes used

  hipLaunchKernelGGL(pack_w3_kernel, dim3(120), dim3(256), 0, stream,
                     W30, W31, W32, pack);

  int nsamp = in_sizes[0] / 64;  // 20000
  int nblocks = nsamp / 16;      // 1250
  hipLaunchKernelGGL(tdense_kernel, dim3(nblocks), dim3(256), 0, stream,
                     x0, x1, x2, W10, W20, W11, W21, W12, W22, pack,
                     (float*)d_out);
}

// Round 10
// 217.537 us; speedup vs baseline: 2.7132x; 1.0181x over previous
//
#include <hip/hip_runtime.h>

// R13 = R3 + explicit per-round B-prefetch into registers.
// Each round now issues its 8 global_load_dwordx4 B-fragment loads BEFORE the
// zgen VALU block (loadB -> zgenv -> mfma2p), guaranteeing the L2 latency is
// hidden under zgen instead of stalling the MFMA cluster. Pure reordering of
// read-only global loads: no sync/layout/numeric change vs the verified R3.
// r=0's extra pc8/pc16 tiles and the zgen-less r=18 keep the original in-line
// load path (mfma2). Occupancy is LDS-limited (2 blocks/CU) so the ~32 extra
// live VGPRs do not reduce residency (launch_bounds(256,2) -> VGPR cap >> this).

typedef __attribute__((ext_vector_type(4))) float f32x4;
typedef __attribute__((ext_vector_type(4))) float f4;
typedef __attribute__((ext_vector_type(2))) float f2;
typedef __attribute__((ext_vector_type(8))) short short8;
typedef unsigned short ushort_t;
typedef unsigned int uint32;

__device__ __forceinline__ uint32 bfb(float x) {
  uint32 u = __float_as_uint(x);
  return (u + 0x7fffu + ((u >> 16) & 1u)) >> 16;  // RNE fp32->bf16 (pack kernel)
}
// round-half-away pack of 2 fp32 -> packed bf16x2: 2 adds + 1 v_perm
__device__ __forceinline__ uint32 pack2f(f2 z) {
  uint32 lo = __float_as_uint(z.x) + 0x8000u;
  uint32 hi = __float_as_uint(z.y) + 0x8000u;
  return __builtin_amdgcn_perm(hi, lo, 0x07060302u);
}

#define C2   0.7071067811865476f
#define C3   0.5773502691896258f
#define C5   0.4472135954999579f
#define C6   0.4082482904638631f
#define C23  0.8164965809277260f
#define C10  0.3162277660168379f
#define C210 0.6324555320336759f
#define C310 0.5477225575051661f
#define C14  0.2672612419124244f
#define C214 0.5345224838248488f
#define C314 0.4629100498862757f

// ---------------- W3 pre-pack: B-fragment order, bf16, norm folded ----------------
__global__ __launch_bounds__(256) void pack_w3_kernel(
    const float* __restrict__ W30, const float* __restrict__ W31,
    const float* __restrict__ W32, ushort_t* __restrict__ pack) {
  int lc = blockIdx.x;
  int t = threadIdx.x >> 6;
  int lam = threadIdx.x & 63;
  const float* W;
  int mb;
  float nrm;
  if (lc < 24) {
    W = W30; mb = lc * 32; nrm = 0.036084391824351615f;        // 1/sqrt(768)
  } else if (lc < 72) {
    W = W31; mb = (lc - 24) * 32; nrm = 0.025515518153991442f; // 1/sqrt(1536)
  } else {
    W = W32; mb = (lc - 72) * 32; nrm = 0.025515518153991442f;
  }
  int w = t * 16 + (lam & 15);
  int m0 = mb + (lam >> 4) * 8;
  ushort_t* dst = pack + ((size_t)(lc * 4 + t) * 64 + lam) * 8;
#pragma unroll
  for (int j = 0; j < 8; ++j)
    dst[j] = (ushort_t)bfb(W[(size_t)(m0 + j) * 64 + w] * nrm);
}

// ---------------- z generation (unchanged from R2/R3) ----------------
// b_s: [s][9 jslots][16 v] floats, s-stride 148 (20 mod 32 -> conflict-free bcast)
template <int NK, int JD, class F>
__device__ __forceinline__ void zgenv(const float* bsj, ushort_t* zrow, F f) {
  uint32 zp[NK][8];
#pragma unroll
  for (int oc = 0; oc < 2; ++oc) {
    f2 bb4[JD][4];
#pragma unroll
    for (int j = 0; j < JD; ++j) {
      f4 lo = *(const f4*)(bsj + j * 16 + oc * 8);
      f4 hi = *(const f4*)(bsj + j * 16 + oc * 8 + 4);
      bb4[j][0] = lo.xy; bb4[j][1] = lo.zw;
      bb4[j][2] = hi.xy; bb4[j][3] = hi.zw;
    }
#pragma unroll
    for (int q = 0; q < 4; ++q) {
      f2 bcol[JD], z[NK];
#pragma unroll
      for (int j = 0; j < JD; ++j) bcol[j] = bb4[j][q];
      f(bcol, z);
#pragma unroll
      for (int k = 0; k < NK; ++k) zp[k][oc * 4 + q] = pack2f(z[k]);
    }
  }
#pragma unroll
  for (int k = 0; k < NK; ++k) {
    uint32* d = (uint32*)(zrow + k * (16 * 264));
    *(uint4*)(d) = make_uint4(zp[k][0], zp[k][1], zp[k][2], zp[k][3]);
    *(uint4*)(d + 4) = make_uint4(zp[k][4], zp[k][5], zp[k][6], zp[k][7]);
  }
}

// ---------------- B-fragment prefetch: this wave's 4 K-chunks x 2 w-tiles ----------
struct Bfrag {
  short8 B0[4];
  short8 B1[4];
};

__device__ __forceinline__ Bfrag loadB(const ushort_t* pk, int pcbase, int h,
                                       int wt0, int lane) {
  Bfrag f;
  const ushort_t* bb = pk + ((size_t)((pcbase + h * 4) * 4 + wt0) * 64 + lane) * 8;
#pragma unroll
  for (int c = 0; c < 4; ++c) {
    f.B0[c] = *(const short8*)(bb + (size_t)c * 2048);
    f.B1[c] = *(const short8*)(bb + (size_t)c * 2048 + 512);
  }
  return f;
}

// ---------------- MFMA with preloaded B: NROW k-rows, 4 chunks, 2 w-tiles ----------
template <int NROW>
__device__ __forceinline__ void mfma2p(const ushort_t* zb, const Bfrag& f,
                                       int h, int lane, f32x4* accA, f32x4* accB) {
  const int srow = lane & 15, quad = lane >> 4;
  const ushort_t* ab = zb + srow * 264 + quad * 8 + h * 128;
#pragma unroll
  for (int c = 0; c < 4; ++c) {
#pragma unroll
    for (int rt = 0; rt < NROW; ++rt) {
      short8 A = *(const short8*)(ab + rt * (16 * 264) + c * 32);
      accA[rt] = __builtin_amdgcn_mfma_f32_16x16x32_bf16(A, f.B0[c], accA[rt], 0, 0, 0);
      accB[rt] = __builtin_amdgcn_mfma_f32_16x16x32_bf16(A, f.B1[c], accB[rt], 0, 0, 0);
    }
  }
}

// ---------------- MFMA with in-line B load (r=0 extras, r=18) ----------------
template <int NROW>
__device__ __forceinline__ void mfma2(const ushort_t* zb, const ushort_t* pk,
                                      int pcbase, int h, int wt0, int lane,
                                      f32x4* accA, f32x4* accB) {
  const int srow = lane & 15, quad = lane >> 4;
  const ushort_t* ab = zb + srow * 264 + quad * 8 + h * 128;
  const ushort_t* bb = pk + ((size_t)((pcbase + h * 4) * 4 + wt0) * 64 + lane) * 8;
#pragma unroll
  for (int c = 0; c < 4; ++c) {
    short8 B0 = *(const short8*)(bb + (size_t)c * 2048);
    short8 B1 = *(const short8*)(bb + (size_t)c * 2048 + 512);
#pragma unroll
    for (int rt = 0; rt < NROW; ++rt) {
      short8 A = *(const short8*)(ab + rt * (16 * 264) + c * 32);
      accA[rt] = __builtin_amdgcn_mfma_f32_16x16x32_bf16(A, B0, accA[rt], 0, 0, 0);
      accB[rt] = __builtin_amdgcn_mfma_f32_16x16x32_bf16(A, B1, accB[rt], 0, 0, 0);
    }
  }
}

#define ZB 12672  // one ping-pong buffer: 3 slots x 16 rows x 264 ushorts

// ---------------- main fused kernel ----------------
__global__ __launch_bounds__(256, 2) void tdense_kernel(
    const float* __restrict__ x0, const float* __restrict__ x1,
    const float* __restrict__ x2, const float* __restrict__ W10,
    const float* __restrict__ W20, const float* __restrict__ W11,
    const float* __restrict__ W21, const float* __restrict__ W12,
    const float* __restrict__ W22, const ushort_t* __restrict__ pack,
    float* __restrict__ out) {
  __shared__ float b_s[2368];                        // 9.25 KB
  __shared__ __align__(16) ushort_t zbuf[2 * ZB];    // 50.7 KB (2 buffers x 3 slots)

  const int tid = threadIdx.x;
  const int nbase = blockIdx.x * 16;
  const int s = tid >> 4, v = tid & 15;

  // ---- Phase 0: both branch linears; a stays in registers (wave-local b_s) ----
  const int n = nbase + s;
  const float* px0 = x0 + (size_t)n * 64;
  const float* px1 = x1 + (size_t)n * 192;
  const float* px2 = x2 + (size_t)n * 320;
  float a0 = 0.f, a1x = 0.f, a1y = 0.f, a1z = 0.f;
  float a2[5] = {0.f, 0.f, 0.f, 0.f, 0.f};
  float b0 = 0.f, b1x = 0.f, b1y = 0.f, b1z = 0.f;
  float b2[5] = {0.f, 0.f, 0.f, 0.f, 0.f};
  for (int u4 = 0; u4 < 16; ++u4) {
    f4 xv0 = *(const f4*)(px0 + u4 * 4);
    f4 xa = *(const f4*)(px1 + u4 * 12);
    f4 xb = *(const f4*)(px1 + u4 * 12 + 4);
    f4 xc = *(const f4*)(px1 + u4 * 12 + 8);
    f4 ya = *(const f4*)(px2 + u4 * 20);
    f4 yb = *(const f4*)(px2 + u4 * 20 + 4);
    f4 yc = *(const f4*)(px2 + u4 * 20 + 8);
    f4 yd = *(const f4*)(px2 + u4 * 20 + 12);
    f4 ye = *(const f4*)(px2 + u4 * 20 + 16);
    float x1e[12], x2e[20];
#pragma unroll
    for (int e = 0; e < 4; ++e) { x1e[e] = xa[e]; x1e[4 + e] = xb[e]; x1e[8 + e] = xc[e]; }
#pragma unroll
    for (int e = 0; e < 4; ++e) {
      x2e[e] = ya[e]; x2e[4 + e] = yb[e]; x2e[8 + e] = yc[e];
      x2e[12 + e] = yd[e]; x2e[16 + e] = ye[e];
    }
#pragma unroll
    for (int r = 0; r < 4; ++r) {
      int u = u4 * 4 + r;
      float wa0 = W10[u * 16 + v], wb0 = W20[u * 16 + v];
      float wa1 = W11[u * 16 + v], wb1 = W21[u * 16 + v];
      float wa2 = W12[u * 16 + v], wb2 = W22[u * 16 + v];
      float xx = xv0[r];
      a0 += xx * wa0; b0 += xx * wb0;
      float e0 = x1e[r * 3 + 0], e1 = x1e[r * 3 + 1], e2 = x1e[r * 3 + 2];
      a1x += e0 * wa1; a1y += e1 * wa1; a1z += e2 * wa1;
      b1x += e0 * wb1; b1y += e1 * wb1; b1z += e2 * wb1;
#pragma unroll
      for (int j = 0; j < 5; ++j) {
        float ev = x2e[r * 5 + j];
        a2[j] += ev * wa2;
        b2[j] += ev * wb2;
      }
    }
  }
  const float inv8 = 0.125f;
  float ar[9];
  ar[0] = a0 * inv8;
  ar[1] = a1x * inv8; ar[2] = a1y * inv8; ar[3] = a1z * inv8;
#pragma unroll
  for (int j = 0; j < 5; ++j) ar[4 + j] = a2[j] * inv8;
  {
    float* bw = b_s + s * 148 + v;
    bw[0] = b0 * inv8;
    bw[16] = b1x * inv8; bw[32] = b1y * inv8; bw[48] = b1z * inv8;
#pragma unroll
    for (int j = 0; j < 5; ++j) bw[64 + j * 16] = b2[j] * inv8;
  }

  const int lane = tid & 63;
  const int wv = tid >> 6;
  const int p2 = (wv & 1) * 2;  // wt0: wave's first w-tile
  const int h = wv >> 1;        // K-half: chunks h*4..h*4+3

  f32x4 aA0, aB0, aA1[3], aB1[3], aA2[5], aB2[5];
  aA0 = (f32x4)(0.f); aB0 = (f32x4)(0.f);
#pragma unroll
  for (int i = 0; i < 3; ++i) { aA1[i] = (f32x4)(0.f); aB1[i] = (f32x4)(0.f); }
#pragma unroll
  for (int i = 0; i < 5; ++i) { aA2[i] = (f32x4)(0.f); aB2[i] = (f32x4)(0.f); }

  const float* bsl0 = b_s + s * 148;
  const float* bsl1 = bsl0 + 16;
  const float* bsl2 = bsl0 + 64;
  ushort_t* z0 = zbuf + s * 264 + v * 16;  // buf0, slot0 row for this thread
  ushort_t* z1 = z0 + ZB;                  // buf1
  const ushort_t* Zb0 = zbuf;
  const ushort_t* Zb1 = zbuf + ZB;

  // ---- R0 zgen -> buf0: p0(000)@slot0/pc0, p4(110)@slot1/pc8, p12(220)@slot2/pc16
  zgenv<1, 1>(bsl0, z0, [&](const f2* b, f2* z) { z[0] = ar[0] * b[0]; });
  zgenv<1, 3>(bsl1, z0 + 4224, [&](const f2* b, f2* z) {
    z[0] = -C3 * (ar[1] * b[0] + ar[2] * b[1] + ar[3] * b[2]);
  });
  zgenv<1, 5>(bsl2, z0 + 8448, [&](const f2* b, f2* z) {
    z[0] = C5 * (ar[4] * b[0] + ar[5] * b[1] + ar[6] * b[2] + ar[7] * b[3] + ar[8] * b[4]);
  });
  __syncthreads();

  // r=0: prefetch pc0 ; zgen R1 (p1(011) NK3) -> buf1 ; mfma R0 (buf0, acc0)
  {
    Bfrag bf = loadB(pack, 0, h, p2, lane);
    zgenv<3, 3>(bsl1, z1, [&](const f2* b, f2* z) {
      z[0] = ar[0] * b[0]; z[1] = ar[0] * b[1]; z[2] = ar[0] * b[2];
    });
    mfma2p<1>(Zb0, bf, h, lane, &aA0, &aB0);
    mfma2<1>(Zb0 + 4224, pack, 8, h, p2, lane, &aA0, &aB0);
    mfma2<1>(Zb0 + 8448, pack, 16, h, p2, lane, &aA0, &aB0);
  }
  __syncthreads();

  // r=1: prefetch pc24 ; zgen R2 (p3(101)) -> buf0 ; mfma R1 (buf1, acc1)
  {
    Bfrag bf = loadB(pack, 24, h, p2, lane);
    zgenv<3, 1>(bsl0, z0, [&](const f2* b, f2* z) {
      z[0] = ar[1] * b[0]; z[1] = ar[2] * b[0]; z[2] = ar[3] * b[0];
    });
    mfma2p<3>(Zb1, bf, h, lane, aA1, aB1);
  }
  __syncthreads();

  // r=2: prefetch pc32 ; zgen R3 (p5(111)) -> buf1 ; mfma R2 (buf0)
  {
    Bfrag bf = loadB(pack, 32, h, p2, lane);
    zgenv<3, 3>(bsl1, z1, [&](const f2* b, f2* z) {
      z[0] = C2 * (ar[2] * b[2] - ar[3] * b[1]);
      z[1] = C2 * (ar[3] * b[0] - ar[1] * b[2]);
      z[2] = C2 * (ar[1] * b[1] - ar[2] * b[0]);
    });
    mfma2p<3>(Zb0, bf, h, lane, aA1, aB1);
  }
  __syncthreads();

  // r=3: prefetch pc40 ; zgen R4 (p7(121)) -> buf0 ; mfma R3 (buf1)
  {
    Bfrag bf = loadB(pack, 40, h, p2, lane);
    zgenv<3, 5>(bsl2, z0, [&](const f2* b, f2* z) {
      z[0] = -C310 * ar[2] * b[1] + C10 * ar[1] * b[2] - C310 * ar[3] * b[0] + C310 * ar[1] * b[4];
      z[1] = -C210 * ar[2] * b[2] - C310 * ar[3] * b[3] - C310 * ar[1] * b[1];
      z[2] = -C310 * ar[2] * b[3] + C10 * ar[3] * b[2] - C310 * ar[1] * b[0] - C310 * ar[3] * b[4];
    });
    mfma2p<3>(Zb1, bf, h, lane, aA1, aB1);
  }
  __syncthreads();

  // r=4: prefetch pc48 ; zgen R5 (p10(211)) -> buf1 ; mfma R4 (buf0)
  {
    Bfrag bf = loadB(pack, 48, h, p2, lane);
    zgenv<3, 3>(bsl1, z1, [&](const f2* b, f2* z) {
      z[0] = -C310 * ar[5] * b[1] + C10 * ar[6] * b[0] - C310 * ar[4] * b[2] + C310 * ar[8] * b[0];
      z[1] = -C210 * ar[6] * b[1] - C310 * ar[7] * b[2] - C310 * ar[5] * b[0];
      z[2] = -C310 * ar[7] * b[1] + C10 * ar[6] * b[2] - C310 * ar[4] * b[0] - C310 * ar[8] * b[2];
    });
    mfma2p<3>(Zb0, bf, h, lane, aA1, aB1);
  }
  __syncthreads();

  // r=5: prefetch pc56 ; zgen R6 (p13(221)) -> buf0 ; mfma R5 (buf1)
  {
    Bfrag bf = loadB(pack, 56, h, p2, lane);
    zgenv<3, 5>(bsl2, z0, [&](const f2* b, f2* z) {
      z[0] = C10 * (ar[8] * b[3] - ar[7] * b[4] + ar[4] * b[1] - ar[5] * b[0]) +
             C310 * (ar[7] * b[2] - ar[6] * b[3]);
      z[1] = C10 * (ar[5] * b[3] - ar[7] * b[1]) + C210 * (ar[4] * b[4] - ar[8] * b[0]);
      z[2] = C10 * (ar[8] * b[1] - ar[5] * b[4] + ar[7] * b[0] - ar[4] * b[3]) +
             C310 * (ar[6] * b[1] - ar[5] * b[2]);
    });
    mfma2p<3>(Zb1, bf, h, lane, aA1, aB1);
  }
  __syncthreads();

  // r=6: prefetch pc64 ; zgen R7 (p2(022) rows 0-2) -> buf1 ; mfma R6 (buf0)
  {
    Bfrag bf = loadB(pack, 64, h, p2, lane);
    zgenv<3, 5>(bsl2, z1, [&](const f2* b, f2* z) {
      z[0] = ar[0] * b[0]; z[1] = ar[0] * b[1]; z[2] = ar[0] * b[2];
    });
    mfma2p<3>(Zb0, bf, h, lane, aA1, aB1);
  }
  __syncthreads();

  // r=7: prefetch pc72 ; zgen R8 (p2 rows 3-4) -> buf0 ; mfma R7 (buf1, acc2[0..2])
  {
    Bfrag bf = loadB(pack, 72, h, p2, lane);
    zgenv<2, 5>(bsl2, z0, [&](const f2* b, f2* z) {
      z[0] = ar[0] * b[3]; z[1] = ar[0] * b[4];
    });
    mfma2p<3>(Zb1, bf, h, lane, aA2, aB2);
  }
  __syncthreads();

  // r=8: prefetch pc72 ; zgen R9 (p6(112) rows 0-2) -> buf1 ; mfma R8 (buf0, acc2[3..4])
  {
    Bfrag bf = loadB(pack, 72, h, p2, lane);
    zgenv<3, 3>(bsl1, z1, [&](const f2* b, f2* z) {
      z[0] = C2 * (ar[1] * b[2] + ar[3] * b[0]);
      z[1] = C2 * (ar[2] * b[0] + ar[1] * b[1]);
      z[2] = C23 * ar[2] * b[1] - C6 * (ar[1] * b[0] + ar[3] * b[2]);
    });
    mfma2p<2>(Zb0, bf, h, lane, aA2 + 3, aB2 + 3);
  }
  __syncthreads();

  // r=9: prefetch pc80 ; zgen R10 (p6 rows 3-4) -> buf0 ; mfma R9 (buf1, acc2[0..2])
  {
    Bfrag bf = loadB(pack, 80, h, p2, lane);
    zgenv<2, 3>(bsl1, z0, [&](const f2* b, f2* z) {
      z[0] = C2 * (ar[2] * b[2] + ar[3] * b[1]);
      z[1] = C2 * (ar[3] * b[2] - ar[1] * b[0]);
    });
    mfma2p<3>(Zb1, bf, h, lane, aA2, aB2);
  }
  __syncthreads();

  // r=10: prefetch pc80 ; zgen R11 (p8(122) rows 0-2) -> buf1 ; mfma R10 (buf0, acc2[3..4])
  {
    Bfrag bf = loadB(pack, 80, h, p2, lane);
    zgenv<3, 5>(bsl2, z1, [&](const f2* b, f2* z) {
      z[0] = C23 * ar[2] * b[4] + C6 * ar[1] * b[1] - C6 * ar[3] * b[3];
      z[1] = C6 * ar[2] * b[3] - C6 * ar[1] * b[0] - C2 * ar[3] * b[2] - C6 * ar[3] * b[4];
      z[2] = C2 * (ar[3] * b[1] - ar[1] * b[3]);
    });
    mfma2p<2>(Zb0, bf, h, lane, aA2 + 3, aB2 + 3);
  }
  __syncthreads();

  // r=11: prefetch pc88 ; zgen R12 (p8 rows 3-4) -> buf0 ; mfma R11 (buf1, acc2[0..2])
  {
    Bfrag bf = loadB(pack, 88, h, p2, lane);
    zgenv<2, 5>(bsl2, z0, [&](const f2* b, f2* z) {
      z[0] = -C6 * ar[2] * b[1] + C2 * ar[1] * b[2] + C6 * ar[3] * b[0] - C6 * ar[1] * b[4];
      z[1] = -C23 * ar[2] * b[0] + C6 * ar[1] * b[3] + C6 * ar[3] * b[1];
    });
    mfma2p<3>(Zb1, bf, h, lane, aA2, aB2);
  }
  __syncthreads();

  // r=12: prefetch pc88 ; zgen R13 (p9(202) rows 0-2) -> buf1 ; mfma R12 (buf0, acc2[3..4])
  {
    Bfrag bf = loadB(pack, 88, h, p2, lane);
    zgenv<3, 1>(bsl0, z1, [&](const f2* b, f2* z) {
      z[0] = ar[4] * b[0]; z[1] = ar[5] * b[0]; z[2] = ar[6] * b[0];
    });
    mfma2p<2>(Zb0, bf, h, lane, aA2 + 3, aB2 + 3);
  }
  __syncthreads();

  // r=13: prefetch pc96 ; zgen R14 (p9 rows 3-4) -> buf0 ; mfma R13 (buf1, acc2[0..2])
  {
    Bfrag bf = loadB(pack, 96, h, p2, lane);
    zgenv<2, 1>(bsl0, z0, [&](const f2* b, f2* z) {
      z[0] = ar[7] * b[0]; z[1] = ar[8] * b[0];
    });
    mfma2p<3>(Zb1, bf, h, lane, aA2, aB2);
  }
  __syncthreads();

  // r=14: prefetch pc96 ; zgen R15 (p11(212) rows 0-2) -> buf1 ; mfma R14 (buf0, acc2[3..4])
  {
    Bfrag bf = loadB(pack, 96, h, p2, lane);
    zgenv<3, 3>(bsl1, z1, [&](const f2* b, f2* z) {
      z[0] = -C23 * ar[8] * b[1] - C6 * ar[5] * b[0] + C6 * ar[7] * b[2];
      z[1] = -C6 * ar[7] * b[1] + C6 * ar[4] * b[0] + C2 * ar[6] * b[2] + C6 * ar[8] * b[2];
      z[2] = C2 * (ar[7] * b[0] - ar[5] * b[2]);
    });
    mfma2p<2>(Zb0, bf, h, lane, aA2 + 3, aB2 + 3);
  }
  __syncthreads();

  // r=15: prefetch pc104 ; zgen R16 (p11 rows 3-4) -> buf0 ; mfma R15 (buf1, acc2[0..2])
  {
    Bfrag bf = loadB(pack, 104, h, p2, lane);
    zgenv<2, 3>(bsl1, z0, [&](const f2* b, f2* z) {
      z[0] = C6 * ar[5] * b[1] - C2 * ar[6] * b[0] - C6 * ar[4] * b[2] + C6 * ar[8] * b[0];
      z[1] = C23 * ar[4] * b[1] - C6 * ar[7] * b[0] - C6 * ar[5] * b[2];
    });
    mfma2p<3>(Zb1, bf, h, lane, aA2, aB2);
  }
  __syncthreads();

  // r=16: prefetch pc104 ; zgen R17 (p14(222) rows 0-2) -> buf1 ; mfma R16 (buf0, acc2[3..4])
  {
    Bfrag bf = loadB(pack, 104, h, p2, lane);
    zgenv<3, 5>(bsl2, z1, [&](const f2* b, f2* z) {
      z[0] = C214 * (ar[6] * b[0] + ar[4] * b[2]) - C314 * (ar[5] * b[3] + ar[7] * b[1]);
      z[1] = -C14 * (ar[6] * b[1] + ar[5] * b[2]) + C314 * (ar[5] * b[4] + ar[8] * b[1]) -
             C314 * (ar[7] * b[0] + ar[4] * b[3]);
      z[2] = -C214 * ar[6] * b[2] - C14 * (ar[5] * b[1] + ar[7] * b[3]) +
             C214 * (ar[4] * b[0] + ar[8] * b[4]);
    });
    mfma2p<2>(Zb0, bf, h, lane, aA2 + 3, aB2 + 3);
  }
  __syncthreads();

  // r=17: prefetch pc112 ; zgen R18 (p14 rows 3-4) -> buf0 ; mfma R17 (buf1, acc2[0..2])
  {
    Bfrag bf = loadB(pack, 112, h, p2, lane);
    zgenv<2, 5>(bsl2, z0, [&](const f2* b, f2* z) {
      z[0] = -C14 * (ar[6] * b[3] + ar[7] * b[2]) - C314 * (ar[5] * b[0] + ar[4] * b[1]) -
             C314 * (ar[7] * b[4] + ar[8] * b[3]);
      z[1] = C214 * (ar[6] * b[4] + ar[8] * b[2]) + C314 * (ar[5] * b[1] - ar[7] * b[3]);
    });
    mfma2p<3>(Zb1, bf, h, lane, aA2, aB2);
  }
  __syncthreads();

  // r=18: mfma R18 (buf0, pc112, acc2[3..4]) -- no zgen to hide under, in-line loads
  mfma2<2>(Zb0, pack, 112, h, p2, lane, aA2 + 3, aB2 + 3);
  __syncthreads();  // all reads of zbuf done before reduction overwrites it

  // ---- Cross-wave K-half reduction via LDS, then global store (h==1 waves) ----
  float* red = (float*)zbuf;
  const int col = lane & 15, quad = lane >> 4;
  if (h == 0) {
#pragma unroll
    for (int pp = 0; pp < 2; ++pp) {
      int wt = p2 + pp;
      const f32x4* src0 = pp ? &aB0 : &aA0;
      const f32x4* src1 = pp ? aB1 : aA1;
      const f32x4* src2 = pp ? aB2 : aA2;
      *(f4*)(red + (wt * 9 + 0) * 256 + lane * 4) = src0[0];
#pragma unroll
      for (int o = 0; o < 3; ++o)
        *(f4*)(red + (wt * 9 + 1 + o) * 256 + lane * 4) = src1[o];
#pragma unroll
      for (int o = 0; o < 5; ++o)
        *(f4*)(red + (wt * 9 + 4 + o) * 256 + lane * 4) = src2[o];
    }
  }
  __syncthreads();
  if (h == 1) {
    aA0 += *(const f4*)(red + (p2 * 9 + 0) * 256 + lane * 4);
    aB0 += *(const f4*)(red + ((p2 + 1) * 9 + 0) * 256 + lane * 4);
#pragma unroll
    for (int o = 0; o < 3; ++o) {
      aA1[o] += *(const f4*)(red + (p2 * 9 + 1 + o) * 256 + lane * 4);
      aB1[o] += *(const f4*)(red + ((p2 + 1) * 9 + 1 + o) * 256 + lane * 4);
    }
#pragma unroll
    for (int o = 0; o < 5; ++o) {
      aA2[o] += *(const f4*)(red + (p2 * 9 + 4 + o) * 256 + lane * 4);
      aB2[o] += *(const f4*)(red + ((p2 + 1) * 9 + 4 + o) * 256 + lane * 4);
    }
    const int w0 = p2 * 16 + col, w1 = w0 + 16;
#pragma unroll
    for (int r = 0; r < 4; ++r) {
      int so = quad * 4 + r;
      float* row = out + (size_t)(nbase + so) * 576;
      row[w0] = aA0[r];
      row[w1] = aB0[r];
      row[64 + w0 * 3 + 0] = aA1[0][r];
      row[64 + w0 * 3 + 1] = aA1[1][r];
      row[64 + w0 * 3 + 2] = aA1[2][r];
      row[64 + w1 * 3 + 0] = aB1[0][r];
      row[64 + w1 * 3 + 1] = aB1[1][r];
      row[64 + w1 * 3 + 2] = aB1[2][r];
#pragma unroll
      for (int k = 0; k < 5; ++k) {
        row[256 + w0 * 5 + k] = aA2[k][r];
        row[256 + w1 * 5 + k] = aB2[k][r];
      }
    }
  }
}

extern "C" void kernel_launch(void* const* d_in, const int* in_sizes, int n_in,
                              void* d_out, int out_size, void* d_ws, size_t ws_size,
                              hipStream_t stream) {
  const float* x0 = (const float*)d_in[0];
  const float* x1 = (const float*)d_in[1];
  const float* x2 = (const float*)d_in[2];
  const float* W10 = (const float*)d_in[3];
  const float* W20 = (const float*)d_in[4];
  const float* W11 = (const float*)d_in[5];
  const float* W21 = (const float*)d_in[6];
  const float* W12 = (const float*)d_in[7];
  const float* W22 = (const float*)d_in[8];
  const float* W30 = (const float*)d_in[9];
  const float* W31 = (const float*)d_in[10];
  const float* W32 = (const float*)d_in[11];
  ushort_t* pack = (ushort_t*)d_ws;  // 491,520 bytes used

  hipLaunchKernelGGL(pack_w3_kernel, dim3(120), dim3(256), 0, stream,
                     W30, W31, W32, pack);

  int nsamp = in_sizes[0] / 64;  // 20000
  int nblocks = nsamp / 16;      // 1250
  hipLaunchKernelGGL(tdense_kernel, dim3(nblocks), dim3(256), 0, stream,
                     x0, x1, x2, W10, W20, W11, W21, W12, W22, pack,
                     (float*)d_out);
}

// Round 11
// 212.911 us; speedup vs baseline: 2.7721x; 1.0217x over previous
//
#include <hip/hip_runtime.h>

// R14 = R13 (B-prefetch, 217.5 us session) + B-fragment REUSE across the six
// NK5 row-split round pairs. Pairs (r7,r8)@pc72, (r9,r10)@pc80, (r11,r12)@pc88,
// (r13,r14)@pc96, (r15,r16)@pc104, (r17,r18)@pc112 load identical B fragments;
// the second round of each pair now reuses the live Bfrag registers instead of
// re-issuing 8 global_load_dwordx4 (-48 of ~168 pack loads/wave, and r18's MFMA
// cluster no longer has a load-use stall). Registers persist across barriers;
// loads are read-only: zero semantic change vs the verified R13. Occupancy is
// LDS-limited (2 blocks/CU = 2 waves/SIMD, VGPR cap ~256) so +32 live VGPRs
// cannot reduce residency.

typedef __attribute__((ext_vector_type(4))) float f32x4;
typedef __attribute__((ext_vector_type(4))) float f4;
typedef __attribute__((ext_vector_type(2))) float f2;
typedef __attribute__((ext_vector_type(8))) short short8;
typedef unsigned short ushort_t;
typedef unsigned int uint32;

__device__ __forceinline__ uint32 bfb(float x) {
  uint32 u = __float_as_uint(x);
  return (u + 0x7fffu + ((u >> 16) & 1u)) >> 16;  // RNE fp32->bf16 (pack kernel)
}
// round-half-away pack of 2 fp32 -> packed bf16x2: 2 adds + 1 v_perm
__device__ __forceinline__ uint32 pack2f(f2 z) {
  uint32 lo = __float_as_uint(z.x) + 0x8000u;
  uint32 hi = __float_as_uint(z.y) + 0x8000u;
  return __builtin_amdgcn_perm(hi, lo, 0x07060302u);
}

#define C2   0.7071067811865476f
#define C3   0.5773502691896258f
#define C5   0.4472135954999579f
#define C6   0.4082482904638631f
#define C23  0.8164965809277260f
#define C10  0.3162277660168379f
#define C210 0.6324555320336759f
#define C310 0.5477225575051661f
#define C14  0.2672612419124244f
#define C214 0.5345224838248488f
#define C314 0.4629100498862757f

// ---------------- W3 pre-pack: B-fragment order, bf16, norm folded ----------------
__global__ __launch_bounds__(256) void pack_w3_kernel(
    const float* __restrict__ W30, const float* __restrict__ W31,
    const float* __restrict__ W32, ushort_t* __restrict__ pack) {
  int lc = blockIdx.x;
  int t = threadIdx.x >> 6;
  int lam = threadIdx.x & 63;
  const float* W;
  int mb;
  float nrm;
  if (lc < 24) {
    W = W30; mb = lc * 32; nrm = 0.036084391824351615f;        // 1/sqrt(768)
  } else if (lc < 72) {
    W = W31; mb = (lc - 24) * 32; nrm = 0.025515518153991442f; // 1/sqrt(1536)
  } else {
    W = W32; mb = (lc - 72) * 32; nrm = 0.025515518153991442f;
  }
  int w = t * 16 + (lam & 15);
  int m0 = mb + (lam >> 4) * 8;
  ushort_t* dst = pack + ((size_t)(lc * 4 + t) * 64 + lam) * 8;
#pragma unroll
  for (int j = 0; j < 8; ++j)
    dst[j] = (ushort_t)bfb(W[(size_t)(m0 + j) * 64 + w] * nrm);
}

// ---------------- z generation (unchanged from R2/R3) ----------------
// b_s: [s][9 jslots][16 v] floats, s-stride 148 (20 mod 32 -> conflict-free bcast)
template <int NK, int JD, class F>
__device__ __forceinline__ void zgenv(const float* bsj, ushort_t* zrow, F f) {
  uint32 zp[NK][8];
#pragma unroll
  for (int oc = 0; oc < 2; ++oc) {
    f2 bb4[JD][4];
#pragma unroll
    for (int j = 0; j < JD; ++j) {
      f4 lo = *(const f4*)(bsj + j * 16 + oc * 8);
      f4 hi = *(const f4*)(bsj + j * 16 + oc * 8 + 4);
      bb4[j][0] = lo.xy; bb4[j][1] = lo.zw;
      bb4[j][2] = hi.xy; bb4[j][3] = hi.zw;
    }
#pragma unroll
    for (int q = 0; q < 4; ++q) {
      f2 bcol[JD], z[NK];
#pragma unroll
      for (int j = 0; j < JD; ++j) bcol[j] = bb4[j][q];
      f(bcol, z);
#pragma unroll
      for (int k = 0; k < NK; ++k) zp[k][oc * 4 + q] = pack2f(z[k]);
    }
  }
#pragma unroll
  for (int k = 0; k < NK; ++k) {
    uint32* d = (uint32*)(zrow + k * (16 * 264));
    *(uint4*)(d) = make_uint4(zp[k][0], zp[k][1], zp[k][2], zp[k][3]);
    *(uint4*)(d + 4) = make_uint4(zp[k][4], zp[k][5], zp[k][6], zp[k][7]);
  }
}

// ---------------- B-fragment prefetch: this wave's 4 K-chunks x 2 w-tiles ----------
struct Bfrag {
  short8 B0[4];
  short8 B1[4];
};

__device__ __forceinline__ Bfrag loadB(const ushort_t* pk, int pcbase, int h,
                                       int wt0, int lane) {
  Bfrag f;
  const ushort_t* bb = pk + ((size_t)((pcbase + h * 4) * 4 + wt0) * 64 + lane) * 8;
#pragma unroll
  for (int c = 0; c < 4; ++c) {
    f.B0[c] = *(const short8*)(bb + (size_t)c * 2048);
    f.B1[c] = *(const short8*)(bb + (size_t)c * 2048 + 512);
  }
  return f;
}

// ---------------- MFMA with preloaded B: NROW k-rows, 4 chunks, 2 w-tiles ----------
template <int NROW>
__device__ __forceinline__ void mfma2p(const ushort_t* zb, const Bfrag& f,
                                       int h, int lane, f32x4* accA, f32x4* accB) {
  const int srow = lane & 15, quad = lane >> 4;
  const ushort_t* ab = zb + srow * 264 + quad * 8 + h * 128;
#pragma unroll
  for (int c = 0; c < 4; ++c) {
#pragma unroll
    for (int rt = 0; rt < NROW; ++rt) {
      short8 A = *(const short8*)(ab + rt * (16 * 264) + c * 32);
      accA[rt] = __builtin_amdgcn_mfma_f32_16x16x32_bf16(A, f.B0[c], accA[rt], 0, 0, 0);
      accB[rt] = __builtin_amdgcn_mfma_f32_16x16x32_bf16(A, f.B1[c], accB[rt], 0, 0, 0);
    }
  }
}

// ---------------- MFMA with in-line B load (r=0 pc8/pc16 extras) ----------------
template <int NROW>
__device__ __forceinline__ void mfma2(const ushort_t* zb, const ushort_t* pk,
                                      int pcbase, int h, int wt0, int lane,
                                      f32x4* accA, f32x4* accB) {
  const int srow = lane & 15, quad = lane >> 4;
  const ushort_t* ab = zb + srow * 264 + quad * 8 + h * 128;
  const ushort_t* bb = pk + ((size_t)((pcbase + h * 4) * 4 + wt0) * 64 + lane) * 8;
#pragma unroll
  for (int c = 0; c < 4; ++c) {
    short8 B0 = *(const short8*)(bb + (size_t)c * 2048);
    short8 B1 = *(const short8*)(bb + (size_t)c * 2048 + 512);
#pragma unroll
    for (int rt = 0; rt < NROW; ++rt) {
      short8 A = *(const short8*)(ab + rt * (16 * 264) + c * 32);
      accA[rt] = __builtin_amdgcn_mfma_f32_16x16x32_bf16(A, B0, accA[rt], 0, 0, 0);
      accB[rt] = __builtin_amdgcn_mfma_f32_16x16x32_bf16(A, B1, accB[rt], 0, 0, 0);
    }
  }
}

#define ZB 12672  // one ping-pong buffer: 3 slots x 16 rows x 264 ushorts

// ---------------- main fused kernel ----------------
__global__ __launch_bounds__(256, 2) void tdense_kernel(
    const float* __restrict__ x0, const float* __restrict__ x1,
    const float* __restrict__ x2, const float* __restrict__ W10,
    const float* __restrict__ W20, const float* __restrict__ W11,
    const float* __restrict__ W21, const float* __restrict__ W12,
    const float* __restrict__ W22, const ushort_t* __restrict__ pack,
    float* __restrict__ out) {
  __shared__ float b_s[2368];                        // 9.25 KB
  __shared__ __align__(16) ushort_t zbuf[2 * ZB];    // 50.7 KB (2 buffers x 3 slots)

  const int tid = threadIdx.x;
  const int nbase = blockIdx.x * 16;
  const int s = tid >> 4, v = tid & 15;

  // ---- Phase 0: both branch linears; a stays in registers (wave-local b_s) ----
  const int n = nbase + s;
  const float* px0 = x0 + (size_t)n * 64;
  const float* px1 = x1 + (size_t)n * 192;
  const float* px2 = x2 + (size_t)n * 320;
  float a0 = 0.f, a1x = 0.f, a1y = 0.f, a1z = 0.f;
  float a2[5] = {0.f, 0.f, 0.f, 0.f, 0.f};
  float b0 = 0.f, b1x = 0.f, b1y = 0.f, b1z = 0.f;
  float b2[5] = {0.f, 0.f, 0.f, 0.f, 0.f};
  for (int u4 = 0; u4 < 16; ++u4) {
    f4 xv0 = *(const f4*)(px0 + u4 * 4);
    f4 xa = *(const f4*)(px1 + u4 * 12);
    f4 xb = *(const f4*)(px1 + u4 * 12 + 4);
    f4 xc = *(const f4*)(px1 + u4 * 12 + 8);
    f4 ya = *(const f4*)(px2 + u4 * 20);
    f4 yb = *(const f4*)(px2 + u4 * 20 + 4);
    f4 yc = *(const f4*)(px2 + u4 * 20 + 8);
    f4 yd = *(const f4*)(px2 + u4 * 20 + 12);
    f4 ye = *(const f4*)(px2 + u4 * 20 + 16);
    float x1e[12], x2e[20];
#pragma unroll
    for (int e = 0; e < 4; ++e) { x1e[e] = xa[e]; x1e[4 + e] = xb[e]; x1e[8 + e] = xc[e]; }
#pragma unroll
    for (int e = 0; e < 4; ++e) {
      x2e[e] = ya[e]; x2e[4 + e] = yb[e]; x2e[8 + e] = yc[e];
      x2e[12 + e] = yd[e]; x2e[16 + e] = ye[e];
    }
#pragma unroll
    for (int r = 0; r < 4; ++r) {
      int u = u4 * 4 + r;
      float wa0 = W10[u * 16 + v], wb0 = W20[u * 16 + v];
      float wa1 = W11[u * 16 + v], wb1 = W21[u * 16 + v];
      float wa2 = W12[u * 16 + v], wb2 = W22[u * 16 + v];
      float xx = xv0[r];
      a0 += xx * wa0; b0 += xx * wb0;
      float e0 = x1e[r * 3 + 0], e1 = x1e[r * 3 + 1], e2 = x1e[r * 3 + 2];
      a1x += e0 * wa1; a1y += e1 * wa1; a1z += e2 * wa1;
      b1x += e0 * wb1; b1y += e1 * wb1; b1z += e2 * wb1;
#pragma unroll
      for (int j = 0; j < 5; ++j) {
        float ev = x2e[r * 5 + j];
        a2[j] += ev * wa2;
        b2[j] += ev * wb2;
      }
    }
  }
  const float inv8 = 0.125f;
  float ar[9];
  ar[0] = a0 * inv8;
  ar[1] = a1x * inv8; ar[2] = a1y * inv8; ar[3] = a1z * inv8;
#pragma unroll
  for (int j = 0; j < 5; ++j) ar[4 + j] = a2[j] * inv8;
  {
    float* bw = b_s + s * 148 + v;
    bw[0] = b0 * inv8;
    bw[16] = b1x * inv8; bw[32] = b1y * inv8; bw[48] = b1z * inv8;
#pragma unroll
    for (int j = 0; j < 5; ++j) bw[64 + j * 16] = b2[j] * inv8;
  }

  const int lane = tid & 63;
  const int wv = tid >> 6;
  const int p2 = (wv & 1) * 2;  // wt0: wave's first w-tile
  const int h = wv >> 1;        // K-half: chunks h*4..h*4+3

  f32x4 aA0, aB0, aA1[3], aB1[3], aA2[5], aB2[5];
  aA0 = (f32x4)(0.f); aB0 = (f32x4)(0.f);
#pragma unroll
  for (int i = 0; i < 3; ++i) { aA1[i] = (f32x4)(0.f); aB1[i] = (f32x4)(0.f); }
#pragma unroll
  for (int i = 0; i < 5; ++i) { aA2[i] = (f32x4)(0.f); aB2[i] = (f32x4)(0.f); }

  const float* bsl0 = b_s + s * 148;
  const float* bsl1 = bsl0 + 16;
  const float* bsl2 = bsl0 + 64;
  ushort_t* z0 = zbuf + s * 264 + v * 16;  // buf0, slot0 row for this thread
  ushort_t* z1 = z0 + ZB;                  // buf1
  const ushort_t* Zb0 = zbuf;
  const ushort_t* Zb1 = zbuf + ZB;

  Bfrag bf;  // persists across barriers for the NK5 row-split pairs

  // ---- R0 zgen -> buf0: p0(000)@slot0/pc0, p4(110)@slot1/pc8, p12(220)@slot2/pc16
  zgenv<1, 1>(bsl0, z0, [&](const f2* b, f2* z) { z[0] = ar[0] * b[0]; });
  zgenv<1, 3>(bsl1, z0 + 4224, [&](const f2* b, f2* z) {
    z[0] = -C3 * (ar[1] * b[0] + ar[2] * b[1] + ar[3] * b[2]);
  });
  zgenv<1, 5>(bsl2, z0 + 8448, [&](const f2* b, f2* z) {
    z[0] = C5 * (ar[4] * b[0] + ar[5] * b[1] + ar[6] * b[2] + ar[7] * b[3] + ar[8] * b[4]);
  });
  __syncthreads();

  // r=0: prefetch pc0 ; zgen R1 (p1(011) NK3) -> buf1 ; mfma R0 (buf0, acc0)
  bf = loadB(pack, 0, h, p2, lane);
  zgenv<3, 3>(bsl1, z1, [&](const f2* b, f2* z) {
    z[0] = ar[0] * b[0]; z[1] = ar[0] * b[1]; z[2] = ar[0] * b[2];
  });
  mfma2p<1>(Zb0, bf, h, lane, &aA0, &aB0);
  mfma2<1>(Zb0 + 4224, pack, 8, h, p2, lane, &aA0, &aB0);
  mfma2<1>(Zb0 + 8448, pack, 16, h, p2, lane, &aA0, &aB0);
  __syncthreads();

  // r=1: prefetch pc24 ; zgen R2 (p3(101)) -> buf0 ; mfma R1 (buf1, acc1)
  bf = loadB(pack, 24, h, p2, lane);
  zgenv<3, 1>(bsl0, z0, [&](const f2* b, f2* z) {
    z[0] = ar[1] * b[0]; z[1] = ar[2] * b[0]; z[2] = ar[3] * b[0];
  });
  mfma2p<3>(Zb1, bf, h, lane, aA1, aB1);
  __syncthreads();

  // r=2: prefetch pc32 ; zgen R3 (p5(111)) -> buf1 ; mfma R2 (buf0)
  bf = loadB(pack, 32, h, p2, lane);
  zgenv<3, 3>(bsl1, z1, [&](const f2* b, f2* z) {
    z[0] = C2 * (ar[2] * b[2] - ar[3] * b[1]);
    z[1] = C2 * (ar[3] * b[0] - ar[1] * b[2]);
    z[2] = C2 * (ar[1] * b[1] - ar[2] * b[0]);
  });
  mfma2p<3>(Zb0, bf, h, lane, aA1, aB1);
  __syncthreads();

  // r=3: prefetch pc40 ; zgen R4 (p7(121)) -> buf0 ; mfma R3 (buf1)
  bf = loadB(pack, 40, h, p2, lane);
  zgenv<3, 5>(bsl2, z0, [&](const f2* b, f2* z) {
    z[0] = -C310 * ar[2] * b[1] + C10 * ar[1] * b[2] - C310 * ar[3] * b[0] + C310 * ar[1] * b[4];
    z[1] = -C210 * ar[2] * b[2] - C310 * ar[3] * b[3] - C310 * ar[1] * b[1];
    z[2] = -C310 * ar[2] * b[3] + C10 * ar[3] * b[2] - C310 * ar[1] * b[0] - C310 * ar[3] * b[4];
  });
  mfma2p<3>(Zb1, bf, h, lane, aA1, aB1);
  __syncthreads();

  // r=4: prefetch pc48 ; zgen R5 (p10(211)) -> buf1 ; mfma R4 (buf0)
  bf = loadB(pack, 48, h, p2, lane);
  zgenv<3, 3>(bsl1, z1, [&](const f2* b, f2* z) {
    z[0] = -C310 * ar[5] * b[1] + C10 * ar[6] * b[0] - C310 * ar[4] * b[2] + C310 * ar[8] * b[0];
    z[1] = -C210 * ar[6] * b[1] - C310 * ar[7] * b[2] - C310 * ar[5] * b[0];
    z[2] = -C310 * ar[7] * b[1] + C10 * ar[6] * b[2] - C310 * ar[4] * b[0] - C310 * ar[8] * b[2];
  });
  mfma2p<3>(Zb0, bf, h, lane, aA1, aB1);
  __syncthreads();

  // r=5: prefetch pc56 ; zgen R6 (p13(221)) -> buf0 ; mfma R5 (buf1)
  bf = loadB(pack, 56, h, p2, lane);
  zgenv<3, 5>(bsl2, z0, [&](const f2* b, f2* z) {
    z[0] = C10 * (ar[8] * b[3] - ar[7] * b[4] + ar[4] * b[1] - ar[5] * b[0]) +
           C310 * (ar[7] * b[2] - ar[6] * b[3]);
    z[1] = C10 * (ar[5] * b[3] - ar[7] * b[1]) + C210 * (ar[4] * b[4] - ar[8] * b[0]);
    z[2] = C10 * (ar[8] * b[1] - ar[5] * b[4] + ar[7] * b[0] - ar[4] * b[3]) +
           C310 * (ar[6] * b[1] - ar[5] * b[2]);
  });
  mfma2p<3>(Zb1, bf, h, lane, aA1, aB1);
  __syncthreads();

  // r=6: prefetch pc64 ; zgen R7 (p2(022) rows 0-2) -> buf1 ; mfma R6 (buf0)
  bf = loadB(pack, 64, h, p2, lane);
  zgenv<3, 5>(bsl2, z1, [&](const f2* b, f2* z) {
    z[0] = ar[0] * b[0]; z[1] = ar[0] * b[1]; z[2] = ar[0] * b[2];
  });
  mfma2p<3>(Zb0, bf, h, lane, aA1, aB1);
  __syncthreads();

  // r=7: prefetch pc72 ; zgen R8 (p2 rows 3-4) -> buf0 ; mfma R7 (buf1, acc2[0..2])
  bf = loadB(pack, 72, h, p2, lane);
  zgenv<2, 5>(bsl2, z0, [&](const f2* b, f2* z) {
    z[0] = ar[0] * b[3]; z[1] = ar[0] * b[4];
  });
  mfma2p<3>(Zb1, bf, h, lane, aA2, aB2);
  __syncthreads();

  // r=8: REUSE pc72 ; zgen R9 (p6(112) rows 0-2) -> buf1 ; mfma R8 (buf0, acc2[3..4])
  zgenv<3, 3>(bsl1, z1, [&](const f2* b, f2* z) {
    z[0] = C2 * (ar[1] * b[2] + ar[3] * b[0]);
    z[1] = C2 * (ar[2] * b[0] + ar[1] * b[1]);
    z[2] = C23 * ar[2] * b[1] - C6 * (ar[1] * b[0] + ar[3] * b[2]);
  });
  mfma2p<2>(Zb0, bf, h, lane, aA2 + 3, aB2 + 3);
  __syncthreads();

  // r=9: prefetch pc80 ; zgen R10 (p6 rows 3-4) -> buf0 ; mfma R9 (buf1, acc2[0..2])
  bf = loadB(pack, 80, h, p2, lane);
  zgenv<2, 3>(bsl1, z0, [&](const f2* b, f2* z) {
    z[0] = C2 * (ar[2] * b[2] + ar[3] * b[1]);
    z[1] = C2 * (ar[3] * b[2] - ar[1] * b[0]);
  });
  mfma2p<3>(Zb1, bf, h, lane, aA2, aB2);
  __syncthreads();

  // r=10: REUSE pc80 ; zgen R11 (p8(122) rows 0-2) -> buf1 ; mfma R10 (buf0, acc2[3..4])
  zgenv<3, 5>(bsl2, z1, [&](const f2* b, f2* z) {
    z[0] = C23 * ar[2] * b[4] + C6 * ar[1] * b[1] - C6 * ar[3] * b[3];
    z[1] = C6 * ar[2] * b[3] - C6 * ar[1] * b[0] - C2 * ar[3] * b[2] - C6 * ar[3] * b[4];
    z[2] = C2 * (ar[3] * b[1] - ar[1] * b[3]);
  });
  mfma2p<2>(Zb0, bf, h, lane, aA2 + 3, aB2 + 3);
  __syncthreads();

  // r=11: prefetch pc88 ; zgen R12 (p8 rows 3-4) -> buf0 ; mfma R11 (buf1, acc2[0..2])
  bf = loadB(pack, 88, h, p2, lane);
  zgenv<2, 5>(bsl2, z0, [&](const f2* b, f2* z) {
    z[0] = -C6 * ar[2] * b[1] + C2 * ar[1] * b[2] + C6 * ar[3] * b[0] - C6 * ar[1] * b[4];
    z[1] = -C23 * ar[2] * b[0] + C6 * ar[1] * b[3] + C6 * ar[3] * b[1];
  });
  mfma2p<3>(Zb1, bf, h, lane, aA2, aB2);
  __syncthreads();

  // r=12: REUSE pc88 ; zgen R13 (p9(202) rows 0-2) -> buf1 ; mfma R12 (buf0, acc2[3..4])
  zgenv<3, 1>(bsl0, z1, [&](const f2* b, f2* z) {
    z[0] = ar[4] * b[0]; z[1] = ar[5] * b[0]; z[2] = ar[6] * b[0];
  });
  mfma2p<2>(Zb0, bf, h, lane, aA2 + 3, aB2 + 3);
  __syncthreads();

  // r=13: prefetch pc96 ; zgen R14 (p9 rows 3-4) -> buf0 ; mfma R13 (buf1, acc2[0..2])
  bf = loadB(pack, 96, h, p2, lane);
  zgenv<2, 1>(bsl0, z0, [&](const f2* b, f2* z) {
    z[0] = ar[7] * b[0]; z[1] = ar[8] * b[0];
  });
  mfma2p<3>(Zb1, bf, h, lane, aA2, aB2);
  __syncthreads();

  // r=14: REUSE pc96 ; zgen R15 (p11(212) rows 0-2) -> buf1 ; mfma R14 (buf0, acc2[3..4])
  zgenv<3, 3>(bsl1, z1, [&](const f2* b, f2* z) {
    z[0] = -C23 * ar[8] * b[1] - C6 * ar[5] * b[0] + C6 * ar[7] * b[2];
    z[1] = -C6 * ar[7] * b[1] + C6 * ar[4] * b[0] + C2 * ar[6] * b[2] + C6 * ar[8] * b[2];
    z[2] = C2 * (ar[7] * b[0] - ar[5] * b[2]);
  });
  mfma2p<2>(Zb0, bf, h, lane, aA2 + 3, aB2 + 3);
  __syncthreads();

  // r=15: prefetch pc104 ; zgen R16 (p11 rows 3-4) -> buf0 ; mfma R15 (buf1, acc2[0..2])
  bf = loadB(pack, 104, h, p2, lane);
  zgenv<2, 3>(bsl1, z0, [&](const f2* b, f2* z) {
    z[0] = C6 * ar[5] * b[1] - C2 * ar[6] * b[0] - C6 * ar[4] * b[2] + C6 * ar[8] * b[0];
    z[1] = C23 * ar[4] * b[1] - C6 * ar[7] * b[0] - C6 * ar[5] * b[2];
  });
  mfma2p<3>(Zb1, bf, h, lane, aA2, aB2);
  __syncthreads();

  // r=16: REUSE pc104 ; zgen R17 (p14(222) rows 0-2) -> buf1 ; mfma R16 (buf0, acc2[3..4])
  zgenv<3, 5>(bsl2, z1, [&](const f2* b, f2* z) {
    z[0] = C214 * (ar[6] * b[0] + ar[4] * b[2]) - C314 * (ar[5] * b[3] + ar[7] * b[1]);
    z[1] = -C14 * (ar[6] * b[1] + ar[5] * b[2]) + C314 * (ar[5] * b[4] + ar[8] * b[1]) -
           C314 * (ar[7] * b[0] + ar[4] * b[3]);
    z[2] = -C214 * ar[6] * b[2] - C14 * (ar[5] * b[1] + ar[7] * b[3]) +
           C214 * (ar[4] * b[0] + ar[8] * b[4]);
  });
  mfma2p<2>(Zb0, bf, h, lane, aA2 + 3, aB2 + 3);
  __syncthreads();

  // r=17: prefetch pc112 ; zgen R18 (p14 rows 3-4) -> buf0 ; mfma R17 (buf1, acc2[0..2])
  bf = loadB(pack, 112, h, p2, lane);
  zgenv<2, 5>(bsl2, z0, [&](const f2* b, f2* z) {
    z[0] = -C14 * (ar[6] * b[3] + ar[7] * b[2]) - C314 * (ar[5] * b[0] + ar[4] * b[1]) -
           C314 * (ar[7] * b[4] + ar[8] * b[3]);
    z[1] = C214 * (ar[6] * b[4] + ar[8] * b[2]) + C314 * (ar[5] * b[1] - ar[7] * b[3]);
  });
  mfma2p<3>(Zb1, bf, h, lane, aA2, aB2);
  __syncthreads();

  // r=18: REUSE pc112 ; mfma R18 (buf0, acc2[3..4]) -- no loads at all
  mfma2p<2>(Zb0, bf, h, lane, aA2 + 3, aB2 + 3);
  __syncthreads();  // all reads of zbuf done before reduction overwrites it

  // ---- Cross-wave K-half reduction via LDS, then global store (h==1 waves) ----
  float* red = (float*)zbuf;
  const int col = lane & 15, quad = lane >> 4;
  if (h == 0) {
#pragma unroll
    for (int pp = 0; pp < 2; ++pp) {
      int wt = p2 + pp;
      const f32x4* src0 = pp ? &aB0 : &aA0;
      const f32x4* src1 = pp ? aB1 : aA1;
      const f32x4* src2 = pp ? aB2 : aA2;
      *(f4*)(red + (wt * 9 + 0) * 256 + lane * 4) = src0[0];
#pragma unroll
      for (int o = 0; o < 3; ++o)
        *(f4*)(red + (wt * 9 + 1 + o) * 256 + lane * 4) = src1[o];
#pragma unroll
      for (int o = 0; o < 5; ++o)
        *(f4*)(red + (wt * 9 + 4 + o) * 256 + lane * 4) = src2[o];
    }
  }
  __syncthreads();
  if (h == 1) {
    aA0 += *(const f4*)(red + (p2 * 9 + 0) * 256 + lane * 4);
    aB0 += *(const f4*)(red + ((p2 + 1) * 9 + 0) * 256 + lane * 4);
#pragma unroll
    for (int o = 0; o < 3; ++o) {
      aA1[o] += *(const f4*)(red + (p2 * 9 + 1 + o) * 256 + lane * 4);
      aB1[o] += *(const f4*)(red + ((p2 + 1) * 9 + 1 + o) * 256 + lane * 4);
    }
#pragma unroll
    for (int o = 0; o < 5; ++o) {
      aA2[o] += *(const f4*)(red + (p2 * 9 + 4 + o) * 256 + lane * 4);
      aB2[o] += *(const f4*)(red + ((p2 + 1) * 9 + 4 + o) * 256 + lane * 4);
    }
    const int w0 = p2 * 16 + col, w1 = w0 + 16;
#pragma unroll
    for (int r = 0; r < 4; ++r) {
      int so = quad * 4 + r;
      float* row = out + (size_t)(nbase + so) * 576;
      row[w0] = aA0[r];
      row[w1] = aB0[r];
      row[64 + w0 * 3 + 0] = aA1[0][r];
      row[64 + w0 * 3 + 1] = aA1[1][r];
      row[64 + w0 * 3 + 2] = aA1[2][r];
      row[64 + w1 * 3 + 0] = aB1[0][r];
      row[64 + w1 * 3 + 1] = aB1[1][r];
      row[64 + w1 * 3 + 2] = aB1[2][r];
#pragma unroll
      for (int k = 0; k < 5; ++k) {
        row[256 + w0 * 5 + k] = aA2[k][r];
        row[256 + w1 * 5 + k] = aB2[k][r];
      }
    }
  }
}

extern "C" void kernel_launch(void* const* d_in, const int* in_sizes, int n_in,
                              void* d_out, int out_size, void* d_ws, size_t ws_size,
                              hipStream_t stream) {
  const float* x0 = (const float*)d_in[0];
  const float* x1 = (const float*)d_in[1];
  const float* x2 = (const float*)d_in[2];
  const float* W10 = (const float*)d_in[3];
  const float* W20 = (const float*)d_in[4];
  const float* W11 = (const float*)d_in[5];
  const float* W21 = (const float*)d_in[6];
  const float* W12 = (const float*)d_in[7];
  const float* W22 = (const float*)d_in[8];
  const float* W30 = (const float*)d_in[9];
  const float* W31 = (const float*)d_in[10];
  const float* W32 = (const float*)d_in[11];
  ushort_t* pack = (ushort_t*)d_ws;  // 491,520 bytes used

  hipLaunchKernelGGL(pack_w3_kernel, dim3(120), dim3(256), 0, stream,
                     W30, W31, W32, pack);

  int nsamp = in_sizes[0] / 64;  // 20000
  int nblocks = nsamp / 16;      // 1250
  hipLaunchKernelGGL(tdense_kernel, dim3(nblocks), dim3(256), 0, stream,
                     x0, x1, x2, W10, W20, W11, W21, W12, W22, pack,
                     (float*)d_out);
}